// Round 5
// baseline (1464.569 us; speedup 1.0000x reference)
//
#include <hip/hip_runtime.h>
#include <hip/hip_bf16.h>

// ---------------------------------------------------------------------------
// CirculantAttention on MI355X — round 5: barrier-free direct-fragment GEMMs.
//
// r4 post-mortem: gemm_cplx showed MfmaUtil 20 / VALU 23 / HBM 21 / Occ 19 —
// latency+barrier bound (2 barriers + serial split2 transpose per K-step),
// FETCH 305MB (8 d-tiles re-fetch X from different XCD L2s).
// r5: activations are pre-transposed ONCE to token-major bf16x2 planes
// (xpose_cplx / xpose_real, BW-bound); GEMMs load A-fragments directly from
// global (no LDS, no barriers, no split in K-loop) and use an XCD-chunked
// block swizzle so d-tiles sharing an A-panel hit the same L2.
// Gate GEMM moved to the end (multiplies silu() into y in place) -> T buffer
// gone; XP (X planes) time-shares its slot with GX (real planes).
//
// ws: W0 69,206,016 | W1 69,206,016 | XP/GX 69,206,016 | PL 5,242,880 |
//     TW 253,952  => 213,114,880 B total (identical to round 4's proven).
// ---------------------------------------------------------------------------

#define BB 8
#define CC 512
#define HH 64
#define SS 4096   // HH*WW
#define WR 33     // WW/2+1
#define PP 2112   // HH*WR

#define TWOPI_64 0.09817477042468103f   // 2*pi/64

typedef float f32x4 __attribute__((ext_vector_type(4)));
typedef __bf16 bf16x8 __attribute__((ext_vector_type(8)));
typedef unsigned short ushort;
typedef ushort ushort8 __attribute__((ext_vector_type(8)));

// PL arena (ushort units)
#define QKV_HI 0
#define QKV_LO 786432
#define GATE_HI 1572864
#define GATE_LO 1835008
#define PROJ_HI 2097152
#define PROJ_LO 2359296
// end 2,621,440 ush = 5,242,880 B

// TW arena (ushort units) — unchanged from round 4
#define TWF_OFF 0
#define TWH0_OFF 12288
#define TWH1_OFF 47104
#define TWH2_OFF 81920
#define TWI_OFF 116736

#define SPX 8650752    // XP plane stride (ushort): 8*2112*512
#define SPG 16777216   // GX plane stride (ushort): 8*4096*512

__device__ __forceinline__ void split2(float x, ushort& h, ushort& l) {
  unsigned bx = __builtin_bit_cast(unsigned, x);
  h = (ushort)(bx >> 16);
  float hf = __builtin_bit_cast(float, bx & 0xffff0000u);
  float lf = x - hf;
  l = (ushort)(__builtin_bit_cast(unsigned, lf) >> 16);
}

__device__ __forceinline__ void gll16(const void* src, void* lds_dst) {
  __builtin_amdgcn_global_load_lds(
      (const __attribute__((address_space(1))) unsigned int*)src,
      (__attribute__((address_space(3))) unsigned int*)lds_dst, 16, 0, 0);
}

#define MFMA16(a, b, c) __builtin_amdgcn_mfma_f32_16x16x32_bf16(a, b, c, 0, 0, 0)

__device__ __forceinline__ void pack8(const float* f, bf16x8& hi, bf16x8& lo) {
  ushort8 hs, ls;
#pragma unroll
  for (int j = 0; j < 8; ++j) { ushort h, l; split2(f[j], h, l); hs[j] = h; ls[j] = l; }
  hi = __builtin_bit_cast(bf16x8, hs);
  lo = __builtin_bit_cast(bf16x8, ls);
}

// ===================== weight pre-split (once per launch) ==================
__global__ __launch_bounds__(256) void prep_w(
    const float* __restrict__ wqkv, const float* __restrict__ wg,
    const float* __restrict__ wp, ushort* __restrict__ planes) {
  int i = blockIdx.x * 256 + threadIdx.x;   // 0 .. 1,310,719
  float v; ushort *hp, *lp;
  if (i < 786432) {
    v = wqkv[i]; hp = planes + QKV_HI + i; lp = planes + QKV_LO + i;
  } else if (i < 1048576) {
    int j = i - 786432;
    v = wg[j]; hp = planes + GATE_HI + j; lp = planes + GATE_LO + j;
  } else {
    int j = i - 1048576;
    v = wp[j]; hp = planes + PROJ_HI + j; lp = planes + PROJ_LO + j;
  }
  ushort h, l; split2(v, h, l);
  *hp = h; *lp = l;
}

// ===================== twiddle pre-split (once per launch) =================
__global__ __launch_bounds__(256) void prep_tw(ushort* __restrict__ tw) {
  int i = blockIdx.x * 256 + threadIdx.x;
  if (i >= 62592) return;
  float val = 0.f; int base, plane, e;
  if (i < 5760) {                      // TWF [80][72]
    e = i; base = TWF_OFF; plane = 5760;
    int n = e / 72, k = e % 72;
    if (n < 66 && k < 64) {
      int kw = n >> 1;
      float s, c; sincosf(TWOPI_64 * (float)((k * kw) & 63), &s, &c);
      val = (n & 1) ? -s : c;
    }
  } else if (i < 57984) {              // TWH[v] [128][136]
    int j = i - 5760; int v = j / 17408; e = j % 17408;
    base = TWH0_OFF + v * 34816; plane = 17408;
    float sgn = (v == 1) ? 1.f : -1.f;
    float scale = (v == 0) ? (1.f / 64.f) : 1.f;
    int n = e / 136, k = e % 136;
    if (k < 128) {
      int kh = n >> 1, q = n & 1, h = k >> 1, p = k & 1;
      float s, c; sincosf(TWOPI_64 * (float)((h * kh) & 63), &s, &c);
      val = (p == q) ? c : ((q == 1) ? sgn * s : -sgn * s);
      val *= scale;
    }
  } else {                             // TWI [64][72]
    e = i - 57984; base = TWI_OFF; plane = 4608;
    int n = e / 72, k = e % 72;
    if (k < 64) {
      int kk = k >> 1, p = k & 1;
      float w = (kk == 0) ? 1.f : 2.f;
      float s, c; sincosf(TWOPI_64 * (float)((n * kk) & 63), &s, &c);
      val = (p ? -s : c) * w * (1.f / 64.f);
    }
  }
  ushort h, l; split2(val, h, l);
  tw[base + e] = h; tw[base + plane + e] = l;
}

// ===================== transpose+split: planar f32 -> token-major bf16 =====
// complex: W0 [b*CC+c][p] float2  ->  XP planes {reH,reL,imH,imL}[b][p][c]
__global__ __launch_bounds__(256) void xpose_cplx(
    const float2* __restrict__ in, ushort* __restrict__ xp) {
  __shared__ float2 tile[64][65];
  int b = blockIdx.z, p0 = blockIdx.x * 64, c0 = blockIdx.y * 64;
  int tid = threadIdx.x;
  int cr = tid >> 2, pq = (tid & 3) * 16;
  const float2* src = in + ((size_t)b * CC + c0 + cr) * PP + p0 + pq;
#pragma unroll
  for (int j = 0; j < 16; ++j) tile[cr][pq + j] = src[j];
  __syncthreads();
  int pr = tid >> 2, cq = (tid & 3) * 16;
  ushort8 rh[2], rl[2], ih[2], il[2];
#pragma unroll
  for (int g = 0; g < 2; ++g)
#pragma unroll
    for (int j = 0; j < 8; ++j) {
      float2 v = tile[cq + g * 8 + j][pr];
      ushort h, l;
      split2(v.x, h, l); rh[g][j] = h; rl[g][j] = l;
      split2(v.y, h, l); ih[g][j] = h; il[g][j] = l;
    }
  size_t ob = ((size_t)b * PP + p0 + pr) * CC + c0 + cq;
#pragma unroll
  for (int g = 0; g < 2; ++g) {
    *reinterpret_cast<ushort8*>(&xp[ob + g * 8]) = rh[g];
    *reinterpret_cast<ushort8*>(&xp[SPX + ob + g * 8]) = rl[g];
    *reinterpret_cast<ushort8*>(&xp[2 * SPX + ob + g * 8]) = ih[g];
    *reinterpret_cast<ushort8*>(&xp[3 * SPX + ob + g * 8]) = il[g];
  }
}

// real: in [b*CC+c][s] f32 -> GX planes {hi,lo}[b][s][c]
__global__ __launch_bounds__(256) void xpose_real(
    const float* __restrict__ in, ushort* __restrict__ gx) {
  __shared__ float tile[64][65];
  int b = blockIdx.z, s0 = blockIdx.x * 64, c0 = blockIdx.y * 64;
  int tid = threadIdx.x;
  int cr = tid >> 2, sq = (tid & 3) * 16;
  const float* src = in + ((size_t)b * CC + c0 + cr) * SS + s0 + sq;
#pragma unroll
  for (int j = 0; j < 16; ++j) tile[cr][sq + j] = src[j];
  __syncthreads();
  int sr = tid >> 2, cq = (tid & 3) * 16;
  ushort8 vh[2], vl[2];
#pragma unroll
  for (int g = 0; g < 2; ++g)
#pragma unroll
    for (int j = 0; j < 8; ++j) {
      ushort h, l; split2(tile[cq + g * 8 + j][sr], h, l);
      vh[g][j] = h; vl[g][j] = l;
    }
  size_t ob = ((size_t)b * SS + s0 + sr) * CC + c0 + cq;
#pragma unroll
  for (int g = 0; g < 2; ++g) {
    *reinterpret_cast<ushort8*>(&gx[ob + g * 8]) = vh[g];
    *reinterpret_cast<ushort8*>(&gx[SPG + ob + g * 8]) = vl[g];
  }
}

// ===================== complex GEMM, direct fragments, no LDS ==============
// MODE 0: qk (out attnf = conj(q)*k)  MODE 1: v (io = conj(A)*v in place)
template <int MODE>
__global__ __launch_bounds__(256) void gemm_cplx_direct(
    const ushort* __restrict__ xp,
    const ushort* __restrict__ w1_hi, const ushort* __restrict__ w1_lo,
    const ushort* __restrict__ w2_hi, const ushort* __restrict__ w2_lo,
    float2* __restrict__ io) {
  // XCD-chunked swizzle: 2112 blocks = 8 chunks x 264 (d-tile fastest in work id)
  int work = (blockIdx.x & 7) * 264 + (blockIdx.x >> 3);
  int b = work / 264, rem = work % 264;
  int m0 = (rem >> 3) * 64, d0 = (rem & 7) * 64;
  int tid = threadIdx.x;
  int lane = tid & 63, wid = tid >> 6;
  int fr = lane & 15, fq = lane >> 4;
  int wm = wid & 1, wd = wid >> 1;

  f32x4 acc[2][2][MODE == 0 ? 4 : 2] = {};
  size_t arow0 = ((size_t)b * PP + (m0 + wm * 32 + fr)) * CC;

  for (int k0 = 0; k0 < CC; k0 += 32) {
    int ko = k0 + fq * 8;
    bf16x8 arh[2], arl[2], aih[2], ail[2];
#pragma unroll
    for (int mt = 0; mt < 2; ++mt) {
      size_t o = arow0 + (size_t)mt * 16 * CC + ko;
      arh[mt] = *reinterpret_cast<const bf16x8*>(&xp[o]);
      arl[mt] = *reinterpret_cast<const bf16x8*>(&xp[SPX + o]);
      aih[mt] = *reinterpret_cast<const bf16x8*>(&xp[2 * SPX + o]);
      ail[mt] = *reinterpret_cast<const bf16x8*>(&xp[3 * SPX + o]);
    }
    bf16x8 w1h[2], w1l[2], w2h[2], w2l[2];
#pragma unroll
    for (int dt = 0; dt < 2; ++dt) {
      size_t wo = (size_t)(d0 + wd * 32 + dt * 16 + fr) * CC + ko;
      w1h[dt] = *reinterpret_cast<const bf16x8*>(&w1_hi[wo]);
      w1l[dt] = *reinterpret_cast<const bf16x8*>(&w1_lo[wo]);
      if (MODE == 0) {
        w2h[dt] = *reinterpret_cast<const bf16x8*>(&w2_hi[wo]);
        w2l[dt] = *reinterpret_cast<const bf16x8*>(&w2_lo[wo]);
      }
    }
#pragma unroll
    for (int mt = 0; mt < 2; ++mt)
#pragma unroll
      for (int dt = 0; dt < 2; ++dt) {
        acc[mt][dt][0] = MFMA16(arh[mt], w1h[dt], acc[mt][dt][0]);
        acc[mt][dt][0] = MFMA16(arh[mt], w1l[dt], acc[mt][dt][0]);
        acc[mt][dt][0] = MFMA16(arl[mt], w1h[dt], acc[mt][dt][0]);
        acc[mt][dt][1] = MFMA16(aih[mt], w1h[dt], acc[mt][dt][1]);
        acc[mt][dt][1] = MFMA16(aih[mt], w1l[dt], acc[mt][dt][1]);
        acc[mt][dt][1] = MFMA16(ail[mt], w1h[dt], acc[mt][dt][1]);
        if (MODE == 0) {
          acc[mt][dt][2] = MFMA16(arh[mt], w2h[dt], acc[mt][dt][2]);
          acc[mt][dt][2] = MFMA16(arh[mt], w2l[dt], acc[mt][dt][2]);
          acc[mt][dt][2] = MFMA16(arl[mt], w2h[dt], acc[mt][dt][2]);
          acc[mt][dt][3] = MFMA16(aih[mt], w2h[dt], acc[mt][dt][3]);
          acc[mt][dt][3] = MFMA16(aih[mt], w2l[dt], acc[mt][dt][3]);
          acc[mt][dt][3] = MFMA16(ail[mt], w2h[dt], acc[mt][dt][3]);
        }
      }
  }
#pragma unroll
  for (int mt = 0; mt < 2; ++mt)
#pragma unroll
    for (int dt = 0; dt < 2; ++dt) {
      int d = d0 + wd * 32 + dt * 16 + fr;
      size_t ob = ((size_t)b * CC + d) * PP + m0 + wm * 32 + mt * 16 + fq * 4;
#pragma unroll
      for (int r = 0; r < 4; ++r) {
        if (MODE == 0) {
          float qr = acc[mt][dt][0][r], qi = acc[mt][dt][1][r];
          float kr = acc[mt][dt][2][r], ki = acc[mt][dt][3][r];
          io[ob + r] = make_float2(qr * kr + qi * ki, qr * ki - qi * kr);
        } else {
          float vr = acc[mt][dt][0][r], vi = acc[mt][dt][1][r];
          float2 a = io[ob + r];
          io[ob + r] = make_float2(a.x * vr + a.y * vi, a.x * vi - a.y * vr);
        }
      }
    }
}

// ===================== real GEMM, direct fragments, no LDS =================
// MODE 0: gate — io[ob] *= silu(z+bias) (in-place on y)
// MODE 1: proj — io[ob] = z + bias
template <int MODE>
__global__ __launch_bounds__(256) void gemm_real_direct(
    const ushort* __restrict__ gx,
    const ushort* __restrict__ w_hi, const ushort* __restrict__ w_lo,
    const float* __restrict__ bias, float* __restrict__ io) {
  // 4096 blocks = 8 chunks x 512 (d-tile fastest in work id)
  int work = (blockIdx.x & 7) * 512 + (blockIdx.x >> 3);
  int b = work / 512, rem = work % 512;
  int m0 = (rem >> 3) * 64, d0 = (rem & 7) * 64;
  int tid = threadIdx.x;
  int lane = tid & 63, wid = tid >> 6;
  int fr = lane & 15, fq = lane >> 4;
  int wm = wid & 1, wd = wid >> 1;

  f32x4 acc[2][2] = {};
  size_t arow0 = ((size_t)b * SS + (m0 + wm * 32 + fr)) * CC;

  for (int k0 = 0; k0 < CC; k0 += 32) {
    int ko = k0 + fq * 8;
    bf16x8 ah[2], al[2], wh[2], wl[2];
#pragma unroll
    for (int mt = 0; mt < 2; ++mt) {
      size_t o = arow0 + (size_t)mt * 16 * CC + ko;
      ah[mt] = *reinterpret_cast<const bf16x8*>(&gx[o]);
      al[mt] = *reinterpret_cast<const bf16x8*>(&gx[SPG + o]);
    }
#pragma unroll
    for (int dt = 0; dt < 2; ++dt) {
      size_t wo = (size_t)(d0 + wd * 32 + dt * 16 + fr) * CC + ko;
      wh[dt] = *reinterpret_cast<const bf16x8*>(&w_hi[wo]);
      wl[dt] = *reinterpret_cast<const bf16x8*>(&w_lo[wo]);
    }
#pragma unroll
    for (int mt = 0; mt < 2; ++mt)
#pragma unroll
      for (int dt = 0; dt < 2; ++dt) {
        acc[mt][dt] = MFMA16(ah[mt], wh[dt], acc[mt][dt]);
        acc[mt][dt] = MFMA16(ah[mt], wl[dt], acc[mt][dt]);
        acc[mt][dt] = MFMA16(al[mt], wh[dt], acc[mt][dt]);
      }
  }
#pragma unroll
  for (int mt = 0; mt < 2; ++mt)
#pragma unroll
    for (int dt = 0; dt < 2; ++dt) {
      int d = d0 + wd * 32 + dt * 16 + fr;
      float bs = bias[d];
      size_t ob = ((size_t)b * CC + d) * SS + m0 + wm * 32 + mt * 16 + fq * 4;
#pragma unroll
      for (int r = 0; r < 4; ++r) {
        float z = acc[mt][dt][r] + bs;
        if (MODE == 0) {
          float t = z / (1.f + __expf(-z));
          io[ob + r] *= t;
        } else {
          io[ob + r] = z;
        }
      }
    }
}

// ===================== DFT-w forward: real rows -> interleaved complex =====
__global__ __launch_bounds__(256) void dftw_fwd(
    const float* __restrict__ in, float* __restrict__ outf,
    const ushort* __restrict__ tw) {
  __shared__ __align__(16) ushort B[12288];
  int tid = threadIdx.x;
  int lane = tid & 63, wid = tid >> 6;
  int fr = lane & 15, fq = lane >> 4;
#pragma unroll
  for (int i = 0; i < 6; ++i)
    gll16((const char*)tw + (i * 256 + tid) * 16,
          (char*)B + (i * 256 + (tid & 192)) * 16);
  __syncthreads();
  bf16x8 bh[5][2], bl[5][2];
#pragma unroll
  for (int nt = 0; nt < 5; ++nt)
#pragma unroll
    for (int ks = 0; ks < 2; ++ks) {
      int o = (nt * 16 + fr) * 72 + ks * 32 + fq * 8;
      bh[nt][ks] = *reinterpret_cast<const bf16x8*>(&B[o]);
      bl[nt][ks] = *reinterpret_cast<const bf16x8*>(&B[5760 + o]);
    }
  for (int chunk = blockIdx.x; chunk < 4096; chunk += gridDim.x) {
    int m0 = chunk * 64 + wid * 16;
    const float* rowp = in + (size_t)(m0 + fr) * 64;
    f32x4 acc[5] = {};
#pragma unroll
    for (int ks = 0; ks < 2; ++ks) {
      float4 v0 = *reinterpret_cast<const float4*>(rowp + ks * 32 + fq * 8);
      float4 v1 = *reinterpret_cast<const float4*>(rowp + ks * 32 + fq * 8 + 4);
      float f[8] = {v0.x, v0.y, v0.z, v0.w, v1.x, v1.y, v1.z, v1.w};
      bf16x8 ah, al; pack8(f, ah, al);
#pragma unroll
      for (int nt = 0; nt < 5; ++nt) {
        acc[nt] = MFMA16(ah, bh[nt][ks], acc[nt]);
        acc[nt] = MFMA16(ah, bl[nt][ks], acc[nt]);
        acc[nt] = MFMA16(al, bh[nt][ks], acc[nt]);
      }
    }
#pragma unroll
    for (int nt = 0; nt < 5; ++nt) {
      int n = nt * 16 + fr;
      if (n < 66) {
#pragma unroll
        for (int r = 0; r < 4; ++r) {
          int m = m0 + fq * 4 + r;
          outf[(size_t)m * 66 + n] = acc[nt][r];
        }
      }
    }
  }
}

// ===================== DFT-h: complex columns, IN-PLACE ====================
__global__ __launch_bounds__(256) void dfth(
    float* __restrict__ io, const ushort* __restrict__ tw) {
  __shared__ __align__(16) ushort B[34816];
  int tid = threadIdx.x;
  int lane = tid & 63, wid = tid >> 6;
  int fr = lane & 15, fq = lane >> 4;
#pragma unroll
  for (int i = 0; i < 17; ++i)
    gll16((const char*)tw + (i * 256 + tid) * 16,
          (char*)B + (i * 256 + (tid & 192)) * 16);
  __syncthreads();
  for (int chunk = blockIdx.x; chunk < 2112; chunk += gridDim.x) {
    int m0 = chunk * 64 + wid * 16;
    int rg = m0 + fr;
    int bc = rg / 33, kw = rg - bc * 33;
    const float* colp = io + ((size_t)bc * PP + kw) * 2;
    bf16x8 ah[4], al[4];
#pragma unroll
    for (int ks = 0; ks < 4; ++ks) {
      float f[8];
#pragma unroll
      for (int e = 0; e < 4; ++e) {
        float2 v = *reinterpret_cast<const float2*>(
            colp + (size_t)(ks * 16 + fq * 4 + e) * WR * 2);
        f[2 * e] = v.x; f[2 * e + 1] = v.y;
      }
      pack8(f, ah[ks], al[ks]);
    }
    f32x4 acc[8] = {};
#pragma unroll
    for (int ks = 0; ks < 4; ++ks)
#pragma unroll
      for (int nt = 0; nt < 8; ++nt) {
        int o = (nt * 16 + fr) * 136 + ks * 32 + fq * 8;
        bf16x8 wh = *reinterpret_cast<const bf16x8*>(&B[o]);
        bf16x8 wl = *reinterpret_cast<const bf16x8*>(&B[17408 + o]);
        acc[nt] = MFMA16(ah[ks], wh, acc[nt]);
        acc[nt] = MFMA16(ah[ks], wl, acc[nt]);
        acc[nt] = MFMA16(al[ks], wh, acc[nt]);
      }
#pragma unroll
    for (int r = 0; r < 4; ++r) {
      int m = m0 + fq * 4 + r;
      int bc2 = m / 33, kw2 = m - bc2 * 33;
      float* outp = io + ((size_t)bc2 * PP + kw2) * 2;
#pragma unroll
      for (int nt = 0; nt < 8; ++nt) {
        int n = nt * 16 + fr;
        int kh = n >> 1, q = n & 1;
        outp[(size_t)kh * WR * 2 + q] = acc[nt][r];
      }
    }
  }
}

// ===================== DFT-w inverse: interleaved complex -> real ==========
__global__ __launch_bounds__(256) void dftw_inv(
    const float* __restrict__ inf, float* __restrict__ out,
    const float* __restrict__ tmul, const ushort* __restrict__ tw) {
  __shared__ __align__(16) ushort B[10240];
  int tid = threadIdx.x;
  int lane = tid & 63, wid = tid >> 6;
  int fr = lane & 15, fq = lane >> 4;
#pragma unroll
  for (int i = 0; i < 5; ++i)
    gll16((const char*)tw + (i * 256 + tid) * 16,
          (char*)B + (i * 256 + (tid & 192)) * 16);
  __syncthreads();
  bf16x8 bh[4][2], bl[4][2];
#pragma unroll
  for (int nt = 0; nt < 4; ++nt)
#pragma unroll
    for (int ks = 0; ks < 2; ++ks) {
      int o = (nt * 16 + fr) * 72 + ks * 32 + fq * 8;
      bh[nt][ks] = *reinterpret_cast<const bf16x8*>(&B[o]);
      bl[nt][ks] = *reinterpret_cast<const bf16x8*>(&B[4608 + o]);
    }
  for (int chunk = blockIdx.x; chunk < 4096; chunk += gridDim.x) {
    int m0 = chunk * 64 + wid * 16;
    const float* rowp = inf + (size_t)(m0 + fr) * 66;
    f32x4 acc[4] = {};
#pragma unroll
    for (int ks = 0; ks < 2; ++ks) {
      float f[8];
#pragma unroll
      for (int e = 0; e < 4; ++e) {
        float2 v = *reinterpret_cast<const float2*>(rowp + ks * 32 + fq * 8 + 2 * e);
        f[2 * e] = v.x; f[2 * e + 1] = v.y;
      }
      bf16x8 ah, al; pack8(f, ah, al);
#pragma unroll
      for (int nt = 0; nt < 4; ++nt) {
        acc[nt] = MFMA16(ah, bh[nt][ks], acc[nt]);
        acc[nt] = MFMA16(ah, bl[nt][ks], acc[nt]);
        acc[nt] = MFMA16(al, bh[nt][ks], acc[nt]);
      }
    }
#pragma unroll
    for (int r = 0; r < 4; ++r) {
      int m = m0 + fq * 4 + r;
      float fr32 = inf[(size_t)m * 66 + 64] * (1.f / 64.f);
#pragma unroll
      for (int nt = 0; nt < 4; ++nt) {
        int x = nt * 16 + fr;
        float res = acc[nt][r] + ((x & 1) ? -fr32 : fr32);
        size_t o = (size_t)m * 64 + x;
        if (tmul) res *= tmul[o];
        out[o] = res;
      }
    }
  }
}

// ========================= softmax over n per (b,c) ========================
__global__ __launch_bounds__(256) void softmax_n(float* __restrict__ a) {
  __shared__ float red[16];
  int bc = blockIdx.x;
  float* p = a + (size_t)bc * SS;
  int t = threadIdx.x;
  float m = -1e30f;
  for (int i = t; i < SS; i += 256) m = fmaxf(m, p[i]);
#pragma unroll
  for (int off = 32; off > 0; off >>= 1) m = fmaxf(m, __shfl_down(m, off));
  if ((t & 63) == 0) red[t >> 6] = m;
  __syncthreads();
  if (t == 0) red[0] = fmaxf(fmaxf(red[0], red[1]), fmaxf(red[2], red[3]));
  __syncthreads();
  m = red[0];
  float s = 0.f;
  for (int i = t; i < SS; i += 256) s += __expf(p[i] - m);
#pragma unroll
  for (int off = 32; off > 0; off >>= 1) s += __shfl_down(s, off);
  if ((t & 63) == 0) red[8 + (t >> 6)] = s;
  __syncthreads();
  if (t == 0) red[4] = red[8] + red[9] + red[10] + red[11];
  __syncthreads();
  float inv = 1.f / red[4];
  for (int i = t; i < SS; i += 256) p[i] = __expf(p[i] - m) * inv;
}

// ===========================================================================
extern "C" void kernel_launch(void* const* d_in, const int* in_sizes, int n_in,
                              void* d_out, int out_size, void* d_ws, size_t ws_size,
                              hipStream_t stream) {
  const float* x      = (const float*)d_in[0];
  const float* w_qkv  = (const float*)d_in[1];
  const float* w_gate = (const float*)d_in[2];
  const float* b_gate = (const float*)d_in[3];
  const float* w_proj = (const float*)d_in[4];
  const float* b_proj = (const float*)d_in[5];
  float* out = (float*)d_out;

  char* ws = (char*)d_ws;
  float*  W0f = (float*)ws;                            // 69,206,016 B
  float2* W0c = (float2*)W0f;
  float*  W1f = (float*)(ws + 69206016);               // 69,206,016 B
  float2* W1c = (float2*)W1f;
  ushort* XP  = (ushort*)(ws + 138412032);             // 69,206,016 B (XP / GX share)
  ushort* GX  = XP;
  ushort* PL  = (ushort*)(ws + 207618048);             //  5,242,880 B
  ushort* TW  = (ushort*)(ws + 212860928);             //    253,952 B (end 213,114,880)

  // 0. pre-split weights + twiddles
  prep_w<<<5120, 256, 0, stream>>>(w_qkv, w_gate, w_proj, PL);
  prep_tw<<<245, 256, 0, stream>>>(TW);
  // 1-2. X = rfft2(x, ortho): w-pass -> W0, h-pass (fwd,1/64) in place
  dftw_fwd<<<1024, 256, 0, stream>>>(x, W0f, TW + TWF_OFF);
  dfth<<<528, 256, 0, stream>>>(W0f, TW + TWH0_OFF);              // X planar in W0
  // 3. X -> token-major bf16x2 planes
  xpose_cplx<<<dim3(33, 8, 8), 256, 0, stream>>>(W0c, XP);        // planar X now dead
  // 4. attnf = conj(q)*k
  gemm_cplx_direct<0><<<2112, 256, 0, stream>>>(XP, PL + QKV_HI, PL + QKV_LO,
                                                PL + QKV_HI + 262144, PL + QKV_LO + 262144, W1c);
  // 5-6. attn = irfft2(attnf, ortho) -> d_out
  dfth<<<528, 256, 0, stream>>>(W1f, TW + TWH1_OFF);
  dftw_inv<<<1024, 256, 0, stream>>>(W1f, out, nullptr, TW + TWI_OFF);
  // 7. softmax over n per (b,c)
  softmax_n<<<BB * CC, 256, 0, stream>>>(out);
  // 8-9. A = rfft2(attn), backward norm (unscaled)
  dftw_fwd<<<1024, 256, 0, stream>>>(out, W1f, TW + TWF_OFF);
  dfth<<<528, 256, 0, stream>>>(W1f, TW + TWH2_OFF);              // A in W1
  // 10. v-GEMM fused with yf = conj(A)*v (in place on W1); XP dead after
  gemm_cplx_direct<1><<<2112, 256, 0, stream>>>(XP, PL + QKV_HI + 524288, PL + QKV_LO + 524288,
                                                nullptr, nullptr, W1c);
  // 11-12. y = irfft2(yf, ortho) -> W0f (planar real)
  dfth<<<528, 256, 0, stream>>>(W1f, TW + TWH1_OFF);
  dftw_inv<<<1024, 256, 0, stream>>>(W1f, W0f, nullptr, TW + TWI_OFF);
  // 13. gate: W0f *= silu(x @ w_gate^T + b_gate)   (GX <- xpose(x))
  xpose_real<<<dim3(64, 8, 8), 256, 0, stream>>>(x, GX);
  gemm_real_direct<0><<<4096, 256, 0, stream>>>(GX, PL + GATE_HI, PL + GATE_LO, b_gate, W0f);
  // 14-15. proj: out = (y.*t) @ w_proj^T + b_proj  (GX <- xpose(y.*t))
  xpose_real<<<dim3(64, 8, 8), 256, 0, stream>>>(W0f, GX);
  gemm_real_direct<1><<<4096, 256, 0, stream>>>(GX, PL + PROJ_HI, PL + PROJ_LO, b_proj, out);
}

// Round 6
// 1137.690 us; speedup vs baseline: 1.2873x; 1.2873x over previous
//
#include <hip/hip_runtime.h>
#include <hip/hip_bf16.h>

// ---------------------------------------------------------------------------
// CirculantAttention on MI355X — round 6: pre-split planes + async LDS GEMMs.
//
// r5 post-mortem: direct-from-global fragments = latency-bound (Mfma 16 /
// VALU 12 / HBM 6 / Occ 20 — nothing busy). r6 restores global_load_lds
// staging (double-buffered, ONE barrier per K-step) on top of r5's
// token-major pre-split bf16x2 planes:
//   - LDS dest linear (T21), global source inverse-XOR-swizzled per lane,
//     ds_read applies the same XOR -> max 4-way conflict.
//   - stage(next) issued right after the barrier; weight loads direct from
//     global (L2-hot, compiler inserts counted vmcnt before MFMA use).
// Everything else identical to round 5 (DFT MFMA passes, xposes, softmax,
// preps, epilogues, XCD swizzle, ws layout 213,114,880 B).
// ---------------------------------------------------------------------------

#define BB 8
#define CC 512
#define HH 64
#define SS 4096   // HH*WW
#define WR 33     // WW/2+1
#define PP 2112   // HH*WR

#define TWOPI_64 0.09817477042468103f   // 2*pi/64

typedef float f32x4 __attribute__((ext_vector_type(4)));
typedef __bf16 bf16x8 __attribute__((ext_vector_type(8)));
typedef unsigned short ushort;
typedef ushort ushort8 __attribute__((ext_vector_type(8)));

// PL arena (ushort units)
#define QKV_HI 0
#define QKV_LO 786432
#define GATE_HI 1572864
#define GATE_LO 1835008
#define PROJ_HI 2097152
#define PROJ_LO 2359296

// TW arena (ushort units)
#define TWF_OFF 0
#define TWH0_OFF 12288
#define TWH1_OFF 47104
#define TWH2_OFF 81920
#define TWI_OFF 116736

#define SPX 8650752    // XP plane stride (ushort): 8*2112*512
#define SPG 16777216   // GX plane stride (ushort): 8*4096*512

__device__ __forceinline__ void split2(float x, ushort& h, ushort& l) {
  unsigned bx = __builtin_bit_cast(unsigned, x);
  h = (ushort)(bx >> 16);
  float hf = __builtin_bit_cast(float, bx & 0xffff0000u);
  float lf = x - hf;
  l = (ushort)(__builtin_bit_cast(unsigned, lf) >> 16);
}

__device__ __forceinline__ void gll16(const void* src, void* lds_dst) {
  __builtin_amdgcn_global_load_lds(
      (const __attribute__((address_space(1))) unsigned int*)src,
      (__attribute__((address_space(3))) unsigned int*)lds_dst, 16, 0, 0);
}

#define MFMA16(a, b, c) __builtin_amdgcn_mfma_f32_16x16x32_bf16(a, b, c, 0, 0, 0)

__device__ __forceinline__ void pack8(const float* f, bf16x8& hi, bf16x8& lo) {
  ushort8 hs, ls;
#pragma unroll
  for (int j = 0; j < 8; ++j) { ushort h, l; split2(f[j], h, l); hs[j] = h; ls[j] = l; }
  hi = __builtin_bit_cast(bf16x8, hs);
  lo = __builtin_bit_cast(bf16x8, ls);
}

// ===================== weight pre-split (once per launch) ==================
__global__ __launch_bounds__(256) void prep_w(
    const float* __restrict__ wqkv, const float* __restrict__ wg,
    const float* __restrict__ wp, ushort* __restrict__ planes) {
  int i = blockIdx.x * 256 + threadIdx.x;   // 0 .. 1,310,719
  float v; ushort *hp, *lp;
  if (i < 786432) {
    v = wqkv[i]; hp = planes + QKV_HI + i; lp = planes + QKV_LO + i;
  } else if (i < 1048576) {
    int j = i - 786432;
    v = wg[j]; hp = planes + GATE_HI + j; lp = planes + GATE_LO + j;
  } else {
    int j = i - 1048576;
    v = wp[j]; hp = planes + PROJ_HI + j; lp = planes + PROJ_LO + j;
  }
  ushort h, l; split2(v, h, l);
  *hp = h; *lp = l;
}

// ===================== twiddle pre-split (once per launch) =================
__global__ __launch_bounds__(256) void prep_tw(ushort* __restrict__ tw) {
  int i = blockIdx.x * 256 + threadIdx.x;
  if (i >= 62592) return;
  float val = 0.f; int base, plane, e;
  if (i < 5760) {                      // TWF [80][72]
    e = i; base = TWF_OFF; plane = 5760;
    int n = e / 72, k = e % 72;
    if (n < 66 && k < 64) {
      int kw = n >> 1;
      float s, c; sincosf(TWOPI_64 * (float)((k * kw) & 63), &s, &c);
      val = (n & 1) ? -s : c;
    }
  } else if (i < 57984) {              // TWH[v] [128][136]
    int j = i - 5760; int v = j / 17408; e = j % 17408;
    base = TWH0_OFF + v * 34816; plane = 17408;
    float sgn = (v == 1) ? 1.f : -1.f;
    float scale = (v == 0) ? (1.f / 64.f) : 1.f;
    int n = e / 136, k = e % 136;
    if (k < 128) {
      int kh = n >> 1, q = n & 1, h = k >> 1, p = k & 1;
      float s, c; sincosf(TWOPI_64 * (float)((h * kh) & 63), &s, &c);
      val = (p == q) ? c : ((q == 1) ? sgn * s : -sgn * s);
      val *= scale;
    }
  } else {                             // TWI [64][72]
    e = i - 57984; base = TWI_OFF; plane = 4608;
    int n = e / 72, k = e % 72;
    if (k < 64) {
      int kk = k >> 1, p = k & 1;
      float w = (kk == 0) ? 1.f : 2.f;
      float s, c; sincosf(TWOPI_64 * (float)((n * kk) & 63), &s, &c);
      val = (p ? -s : c) * w * (1.f / 64.f);
    }
  }
  ushort h, l; split2(val, h, l);
  tw[base + e] = h; tw[base + plane + e] = l;
}

// ===================== transpose+split: planar f32 -> token-major bf16 =====
__global__ __launch_bounds__(256) void xpose_cplx(
    const float2* __restrict__ in, ushort* __restrict__ xp) {
  __shared__ float2 tile[64][65];
  int b = blockIdx.z, p0 = blockIdx.x * 64, c0 = blockIdx.y * 64;
  int tid = threadIdx.x;
  int cr = tid >> 2, pq = (tid & 3) * 16;
  const float2* src = in + ((size_t)b * CC + c0 + cr) * PP + p0 + pq;
#pragma unroll
  for (int j = 0; j < 16; ++j) tile[cr][pq + j] = src[j];
  __syncthreads();
  int pr = tid >> 2, cq = (tid & 3) * 16;
  ushort8 rh[2], rl[2], ih[2], il[2];
#pragma unroll
  for (int g = 0; g < 2; ++g)
#pragma unroll
    for (int j = 0; j < 8; ++j) {
      float2 v = tile[cq + g * 8 + j][pr];
      ushort h, l;
      split2(v.x, h, l); rh[g][j] = h; rl[g][j] = l;
      split2(v.y, h, l); ih[g][j] = h; il[g][j] = l;
    }
  size_t ob = ((size_t)b * PP + p0 + pr) * CC + c0 + cq;
#pragma unroll
  for (int g = 0; g < 2; ++g) {
    *reinterpret_cast<ushort8*>(&xp[ob + g * 8]) = rh[g];
    *reinterpret_cast<ushort8*>(&xp[SPX + ob + g * 8]) = rl[g];
    *reinterpret_cast<ushort8*>(&xp[2 * SPX + ob + g * 8]) = ih[g];
    *reinterpret_cast<ushort8*>(&xp[3 * SPX + ob + g * 8]) = il[g];
  }
}

__global__ __launch_bounds__(256) void xpose_real(
    const float* __restrict__ in, ushort* __restrict__ gx) {
  __shared__ float tile[64][65];
  int b = blockIdx.z, s0 = blockIdx.x * 64, c0 = blockIdx.y * 64;
  int tid = threadIdx.x;
  int cr = tid >> 2, sq = (tid & 3) * 16;
  const float* src = in + ((size_t)b * CC + c0 + cr) * SS + s0 + sq;
#pragma unroll
  for (int j = 0; j < 16; ++j) tile[cr][sq + j] = src[j];
  __syncthreads();
  int sr = tid >> 2, cq = (tid & 3) * 16;
  ushort8 vh[2], vl[2];
#pragma unroll
  for (int g = 0; g < 2; ++g)
#pragma unroll
    for (int j = 0; j < 8; ++j) {
      ushort h, l; split2(tile[cq + g * 8 + j][sr], h, l);
      vh[g][j] = h; vl[g][j] = l;
    }
  size_t ob = ((size_t)b * SS + s0 + sr) * CC + c0 + cq;
#pragma unroll
  for (int g = 0; g < 2; ++g) {
    *reinterpret_cast<ushort8*>(&gx[ob + g * 8]) = vh[g];
    *reinterpret_cast<ushort8*>(&gx[SPG + ob + g * 8]) = vl[g];
  }
}

// ===================== complex GEMM: async-LDS A, direct-global W ==========
// MODE 0: qk (out attnf = conj(q)*k)  MODE 1: v (io = conj(A)*v in place)
template <int MODE>
__global__ __launch_bounds__(256) void gemm_cplx_lds(
    const ushort* __restrict__ xp,
    const ushort* __restrict__ w1_hi, const ushort* __restrict__ w1_lo,
    const ushort* __restrict__ w2_hi, const ushort* __restrict__ w2_lo,
    float2* __restrict__ io) {
  __shared__ ushort sA[2][4][2048];   // [dbuf][plane][64m x 32k], 32 KiB
  // XCD-chunked swizzle: 2112 blocks = 8 chunks x 264 (d-tile fastest)
  int work = (blockIdx.x & 7) * 264 + (blockIdx.x >> 3);
  int b = work / 264, rem = work % 264;
  int m0 = (rem >> 3) * 64, d0 = (rem & 7) * 64;
  int tid = threadIdx.x;
  int lane = tid & 63, wid = tid >> 6;
  int fr = lane & 15, fq = lane >> 4;
  int wm = wid & 1, wd = wid >> 1;

  // staging: lane tid stages LDS linear slot (row=tid>>2, chunk=tid&3);
  // global source chunk pre-swizzled so reader XOR recovers original.
  int sr = tid >> 2, sc = (tid & 3) ^ ((tid >> 2) & 3);
  size_t arow = ((size_t)b * PP + m0 + sr) * CC + sc * 8;
  int wbase = wid * 512;   // ushort offset of this wave's 1 KiB segment

  f32x4 acc[2][2][MODE == 0 ? 4 : 2] = {};

#pragma unroll
  for (int p = 0; p < 4; ++p) gll16(&xp[(size_t)p * SPX + arow], &sA[0][p][wbase]);

  int cur = 0;
  for (int t = 0; t < 16; ++t) {
    __syncthreads();                        // drains stage of buf[cur]
    if (t + 1 < 16) {
      size_t so = arow + (size_t)(t + 1) * 32;
#pragma unroll
      for (int p = 0; p < 4; ++p) gll16(&xp[(size_t)p * SPX + so], &sA[cur ^ 1][p][wbase]);
    }
    int ko = t * 32 + fq * 8;
    bf16x8 w1h[2], w1l[2], w2h[2], w2l[2];
#pragma unroll
    for (int dt = 0; dt < 2; ++dt) {
      size_t wo = (size_t)(d0 + wd * 32 + dt * 16 + fr) * CC + ko;
      w1h[dt] = *reinterpret_cast<const bf16x8*>(&w1_hi[wo]);
      w1l[dt] = *reinterpret_cast<const bf16x8*>(&w1_lo[wo]);
      if (MODE == 0) {
        w2h[dt] = *reinterpret_cast<const bf16x8*>(&w2_hi[wo]);
        w2l[dt] = *reinterpret_cast<const bf16x8*>(&w2_lo[wo]);
      }
    }
    bf16x8 arh[2], arl[2], aih[2], ail[2];
#pragma unroll
    for (int mt = 0; mt < 2; ++mt) {
      int m = wm * 32 + mt * 16 + fr;
      int off = m * 32 + (fq ^ (m & 3)) * 8;
      arh[mt] = *reinterpret_cast<const bf16x8*>(&sA[cur][0][off]);
      arl[mt] = *reinterpret_cast<const bf16x8*>(&sA[cur][1][off]);
      aih[mt] = *reinterpret_cast<const bf16x8*>(&sA[cur][2][off]);
      ail[mt] = *reinterpret_cast<const bf16x8*>(&sA[cur][3][off]);
    }
#pragma unroll
    for (int mt = 0; mt < 2; ++mt)
#pragma unroll
      for (int dt = 0; dt < 2; ++dt) {
        acc[mt][dt][0] = MFMA16(arh[mt], w1h[dt], acc[mt][dt][0]);
        acc[mt][dt][0] = MFMA16(arh[mt], w1l[dt], acc[mt][dt][0]);
        acc[mt][dt][0] = MFMA16(arl[mt], w1h[dt], acc[mt][dt][0]);
        acc[mt][dt][1] = MFMA16(aih[mt], w1h[dt], acc[mt][dt][1]);
        acc[mt][dt][1] = MFMA16(aih[mt], w1l[dt], acc[mt][dt][1]);
        acc[mt][dt][1] = MFMA16(ail[mt], w1h[dt], acc[mt][dt][1]);
        if (MODE == 0) {
          acc[mt][dt][2] = MFMA16(arh[mt], w2h[dt], acc[mt][dt][2]);
          acc[mt][dt][2] = MFMA16(arh[mt], w2l[dt], acc[mt][dt][2]);
          acc[mt][dt][2] = MFMA16(arl[mt], w2h[dt], acc[mt][dt][2]);
          acc[mt][dt][3] = MFMA16(aih[mt], w2h[dt], acc[mt][dt][3]);
          acc[mt][dt][3] = MFMA16(aih[mt], w2l[dt], acc[mt][dt][3]);
          acc[mt][dt][3] = MFMA16(ail[mt], w2h[dt], acc[mt][dt][3]);
        }
      }
    cur ^= 1;
  }
#pragma unroll
  for (int mt = 0; mt < 2; ++mt)
#pragma unroll
    for (int dt = 0; dt < 2; ++dt) {
      int d = d0 + wd * 32 + dt * 16 + fr;
      size_t ob = ((size_t)b * CC + d) * PP + m0 + wm * 32 + mt * 16 + fq * 4;
#pragma unroll
      for (int r = 0; r < 4; ++r) {
        if (MODE == 0) {
          float qr = acc[mt][dt][0][r], qi = acc[mt][dt][1][r];
          float kr = acc[mt][dt][2][r], ki = acc[mt][dt][3][r];
          io[ob + r] = make_float2(qr * kr + qi * ki, qr * ki - qi * kr);
        } else {
          float vr = acc[mt][dt][0][r], vi = acc[mt][dt][1][r];
          float2 a = io[ob + r];
          io[ob + r] = make_float2(a.x * vr + a.y * vi, a.x * vi - a.y * vr);
        }
      }
    }
}

// ===================== real GEMM: async-LDS A, direct-global W =============
// MODE 0: gate — io[ob] *= silu(z+bias)   MODE 1: proj — io[ob] = z + bias
template <int MODE>
__global__ __launch_bounds__(256) void gemm_real_lds(
    const ushort* __restrict__ gx,
    const ushort* __restrict__ w_hi, const ushort* __restrict__ w_lo,
    const float* __restrict__ bias, float* __restrict__ io) {
  __shared__ ushort sA[2][2][2048];   // 16 KiB
  int work = (blockIdx.x & 7) * 512 + (blockIdx.x >> 3);
  int b = work / 512, rem = work % 512;
  int m0 = (rem >> 3) * 64, d0 = (rem & 7) * 64;
  int tid = threadIdx.x;
  int lane = tid & 63, wid = tid >> 6;
  int fr = lane & 15, fq = lane >> 4;
  int wm = wid & 1, wd = wid >> 1;

  int sr = tid >> 2, sc = (tid & 3) ^ ((tid >> 2) & 3);
  size_t arow = ((size_t)b * SS + m0 + sr) * CC + sc * 8;
  int wbase = wid * 512;

  f32x4 acc[2][2] = {};

#pragma unroll
  for (int p = 0; p < 2; ++p) gll16(&gx[(size_t)p * SPG + arow], &sA[0][p][wbase]);

  int cur = 0;
  for (int t = 0; t < 16; ++t) {
    __syncthreads();
    if (t + 1 < 16) {
      size_t so = arow + (size_t)(t + 1) * 32;
#pragma unroll
      for (int p = 0; p < 2; ++p) gll16(&gx[(size_t)p * SPG + so], &sA[cur ^ 1][p][wbase]);
    }
    int ko = t * 32 + fq * 8;
    bf16x8 wh[2], wl[2], ah[2], al[2];
#pragma unroll
    for (int dt = 0; dt < 2; ++dt) {
      size_t wo = (size_t)(d0 + wd * 32 + dt * 16 + fr) * CC + ko;
      wh[dt] = *reinterpret_cast<const bf16x8*>(&w_hi[wo]);
      wl[dt] = *reinterpret_cast<const bf16x8*>(&w_lo[wo]);
    }
#pragma unroll
    for (int mt = 0; mt < 2; ++mt) {
      int m = wm * 32 + mt * 16 + fr;
      int off = m * 32 + (fq ^ (m & 3)) * 8;
      ah[mt] = *reinterpret_cast<const bf16x8*>(&sA[cur][0][off]);
      al[mt] = *reinterpret_cast<const bf16x8*>(&sA[cur][1][off]);
    }
#pragma unroll
    for (int mt = 0; mt < 2; ++mt)
#pragma unroll
      for (int dt = 0; dt < 2; ++dt) {
        acc[mt][dt] = MFMA16(ah[mt], wh[dt], acc[mt][dt]);
        acc[mt][dt] = MFMA16(ah[mt], wl[dt], acc[mt][dt]);
        acc[mt][dt] = MFMA16(al[mt], wh[dt], acc[mt][dt]);
      }
    cur ^= 1;
  }
#pragma unroll
  for (int mt = 0; mt < 2; ++mt)
#pragma unroll
    for (int dt = 0; dt < 2; ++dt) {
      int d = d0 + wd * 32 + dt * 16 + fr;
      float bs = bias[d];
      size_t ob = ((size_t)b * CC + d) * SS + m0 + wm * 32 + mt * 16 + fq * 4;
#pragma unroll
      for (int r = 0; r < 4; ++r) {
        float z = acc[mt][dt][r] + bs;
        if (MODE == 0) {
          float t2 = z / (1.f + __expf(-z));
          io[ob + r] *= t2;
        } else {
          io[ob + r] = z;
        }
      }
    }
}

// ===================== DFT-w forward: real rows -> interleaved complex =====
__global__ __launch_bounds__(256) void dftw_fwd(
    const float* __restrict__ in, float* __restrict__ outf,
    const ushort* __restrict__ tw) {
  __shared__ __align__(16) ushort B[12288];
  int tid = threadIdx.x;
  int lane = tid & 63, wid = tid >> 6;
  int fr = lane & 15, fq = lane >> 4;
#pragma unroll
  for (int i = 0; i < 6; ++i)
    gll16((const char*)tw + (i * 256 + tid) * 16,
          (char*)B + (i * 256 + (tid & 192)) * 16);
  __syncthreads();
  bf16x8 bh[5][2], bl[5][2];
#pragma unroll
  for (int nt = 0; nt < 5; ++nt)
#pragma unroll
    for (int ks = 0; ks < 2; ++ks) {
      int o = (nt * 16 + fr) * 72 + ks * 32 + fq * 8;
      bh[nt][ks] = *reinterpret_cast<const bf16x8*>(&B[o]);
      bl[nt][ks] = *reinterpret_cast<const bf16x8*>(&B[5760 + o]);
    }
  for (int chunk = blockIdx.x; chunk < 4096; chunk += gridDim.x) {
    int m0 = chunk * 64 + wid * 16;
    const float* rowp = in + (size_t)(m0 + fr) * 64;
    f32x4 acc[5] = {};
#pragma unroll
    for (int ks = 0; ks < 2; ++ks) {
      float4 v0 = *reinterpret_cast<const float4*>(rowp + ks * 32 + fq * 8);
      float4 v1 = *reinterpret_cast<const float4*>(rowp + ks * 32 + fq * 8 + 4);
      float f[8] = {v0.x, v0.y, v0.z, v0.w, v1.x, v1.y, v1.z, v1.w};
      bf16x8 ah, al; pack8(f, ah, al);
#pragma unroll
      for (int nt = 0; nt < 5; ++nt) {
        acc[nt] = MFMA16(ah, bh[nt][ks], acc[nt]);
        acc[nt] = MFMA16(ah, bl[nt][ks], acc[nt]);
        acc[nt] = MFMA16(al, bh[nt][ks], acc[nt]);
      }
    }
#pragma unroll
    for (int nt = 0; nt < 5; ++nt) {
      int n = nt * 16 + fr;
      if (n < 66) {
#pragma unroll
        for (int r = 0; r < 4; ++r) {
          int m = m0 + fq * 4 + r;
          outf[(size_t)m * 66 + n] = acc[nt][r];
        }
      }
    }
  }
}

// ===================== DFT-h: complex columns, IN-PLACE ====================
__global__ __launch_bounds__(256) void dfth(
    float* __restrict__ io, const ushort* __restrict__ tw) {
  __shared__ __align__(16) ushort B[34816];
  int tid = threadIdx.x;
  int lane = tid & 63, wid = tid >> 6;
  int fr = lane & 15, fq = lane >> 4;
#pragma unroll
  for (int i = 0; i < 17; ++i)
    gll16((const char*)tw + (i * 256 + tid) * 16,
          (char*)B + (i * 256 + (tid & 192)) * 16);
  __syncthreads();
  for (int chunk = blockIdx.x; chunk < 2112; chunk += gridDim.x) {
    int m0 = chunk * 64 + wid * 16;
    int rg = m0 + fr;
    int bc = rg / 33, kw = rg - bc * 33;
    const float* colp = io + ((size_t)bc * PP + kw) * 2;
    bf16x8 ah[4], al[4];
#pragma unroll
    for (int ks = 0; ks < 4; ++ks) {
      float f[8];
#pragma unroll
      for (int e = 0; e < 4; ++e) {
        float2 v = *reinterpret_cast<const float2*>(
            colp + (size_t)(ks * 16 + fq * 4 + e) * WR * 2);
        f[2 * e] = v.x; f[2 * e + 1] = v.y;
      }
      pack8(f, ah[ks], al[ks]);
    }
    f32x4 acc[8] = {};
#pragma unroll
    for (int ks = 0; ks < 4; ++ks)
#pragma unroll
      for (int nt = 0; nt < 8; ++nt) {
        int o = (nt * 16 + fr) * 136 + ks * 32 + fq * 8;
        bf16x8 wh = *reinterpret_cast<const bf16x8*>(&B[o]);
        bf16x8 wl = *reinterpret_cast<const bf16x8*>(&B[17408 + o]);
        acc[nt] = MFMA16(ah[ks], wh, acc[nt]);
        acc[nt] = MFMA16(ah[ks], wl, acc[nt]);
        acc[nt] = MFMA16(al[ks], wh, acc[nt]);
      }
#pragma unroll
    for (int r = 0; r < 4; ++r) {
      int m = m0 + fq * 4 + r;
      int bc2 = m / 33, kw2 = m - bc2 * 33;
      float* outp = io + ((size_t)bc2 * PP + kw2) * 2;
#pragma unroll
      for (int nt = 0; nt < 8; ++nt) {
        int n = nt * 16 + fr;
        int kh = n >> 1, q = n & 1;
        outp[(size_t)kh * WR * 2 + q] = acc[nt][r];
      }
    }
  }
}

// ===================== DFT-w inverse: interleaved complex -> real ==========
__global__ __launch_bounds__(256) void dftw_inv(
    const float* __restrict__ inf, float* __restrict__ out,
    const float* __restrict__ tmul, const ushort* __restrict__ tw) {
  __shared__ __align__(16) ushort B[10240];
  int tid = threadIdx.x;
  int lane = tid & 63, wid = tid >> 6;
  int fr = lane & 15, fq = lane >> 4;
#pragma unroll
  for (int i = 0; i < 5; ++i)
    gll16((const char*)tw + (i * 256 + tid) * 16,
          (char*)B + (i * 256 + (tid & 192)) * 16);
  __syncthreads();
  bf16x8 bh[4][2], bl[4][2];
#pragma unroll
  for (int nt = 0; nt < 4; ++nt)
#pragma unroll
    for (int ks = 0; ks < 2; ++ks) {
      int o = (nt * 16 + fr) * 72 + ks * 32 + fq * 8;
      bh[nt][ks] = *reinterpret_cast<const bf16x8*>(&B[o]);
      bl[nt][ks] = *reinterpret_cast<const bf16x8*>(&B[4608 + o]);
    }
  for (int chunk = blockIdx.x; chunk < 4096; chunk += gridDim.x) {
    int m0 = chunk * 64 + wid * 16;
    const float* rowp = inf + (size_t)(m0 + fr) * 66;
    f32x4 acc[4] = {};
#pragma unroll
    for (int ks = 0; ks < 2; ++ks) {
      float f[8];
#pragma unroll
      for (int e = 0; e < 4; ++e) {
        float2 v = *reinterpret_cast<const float2*>(rowp + ks * 32 + fq * 8 + 2 * e);
        f[2 * e] = v.x; f[2 * e + 1] = v.y;
      }
      bf16x8 ah, al; pack8(f, ah, al);
#pragma unroll
      for (int nt = 0; nt < 4; ++nt) {
        acc[nt] = MFMA16(ah, bh[nt][ks], acc[nt]);
        acc[nt] = MFMA16(ah, bl[nt][ks], acc[nt]);
        acc[nt] = MFMA16(al, bh[nt][ks], acc[nt]);
      }
    }
#pragma unroll
    for (int r = 0; r < 4; ++r) {
      int m = m0 + fq * 4 + r;
      float fr32 = inf[(size_t)m * 66 + 64] * (1.f / 64.f);
#pragma unroll
      for (int nt = 0; nt < 4; ++nt) {
        int x = nt * 16 + fr;
        float res = acc[nt][r] + ((x & 1) ? -fr32 : fr32);
        size_t o = (size_t)m * 64 + x;
        if (tmul) res *= tmul[o];
        out[o] = res;
      }
    }
  }
}

// ========================= softmax over n per (b,c) ========================
__global__ __launch_bounds__(256) void softmax_n(float* __restrict__ a) {
  __shared__ float red[16];
  int bc = blockIdx.x;
  float* p = a + (size_t)bc * SS;
  int t = threadIdx.x;
  float m = -1e30f;
  for (int i = t; i < SS; i += 256) m = fmaxf(m, p[i]);
#pragma unroll
  for (int off = 32; off > 0; off >>= 1) m = fmaxf(m, __shfl_down(m, off));
  if ((t & 63) == 0) red[t >> 6] = m;
  __syncthreads();
  if (t == 0) red[0] = fmaxf(fmaxf(red[0], red[1]), fmaxf(red[2], red[3]));
  __syncthreads();
  m = red[0];
  float s = 0.f;
  for (int i = t; i < SS; i += 256) s += __expf(p[i] - m);
#pragma unroll
  for (int off = 32; off > 0; off >>= 1) s += __shfl_down(s, off);
  if ((t & 63) == 0) red[8 + (t >> 6)] = s;
  __syncthreads();
  if (t == 0) red[4] = red[8] + red[9] + red[10] + red[11];
  __syncthreads();
  float inv = 1.f / red[4];
  for (int i = t; i < SS; i += 256) p[i] = __expf(p[i] - m) * inv;
}

// ===========================================================================
extern "C" void kernel_launch(void* const* d_in, const int* in_sizes, int n_in,
                              void* d_out, int out_size, void* d_ws, size_t ws_size,
                              hipStream_t stream) {
  const float* x      = (const float*)d_in[0];
  const float* w_qkv  = (const float*)d_in[1];
  const float* w_gate = (const float*)d_in[2];
  const float* b_gate = (const float*)d_in[3];
  const float* w_proj = (const float*)d_in[4];
  const float* b_proj = (const float*)d_in[5];
  float* out = (float*)d_out;

  char* ws = (char*)d_ws;
  float*  W0f = (float*)ws;                            // 69,206,016 B
  float2* W0c = (float2*)W0f;
  float*  W1f = (float*)(ws + 69206016);               // 69,206,016 B
  float2* W1c = (float2*)W1f;
  ushort* XP  = (ushort*)(ws + 138412032);             // 69,206,016 B (XP / GX share)
  ushort* GX  = XP;
  ushort* PL  = (ushort*)(ws + 207618048);             //  5,242,880 B
  ushort* TW  = (ushort*)(ws + 212860928);             //    253,952 B (end 213,114,880)

  // 0. pre-split weights + twiddles
  prep_w<<<5120, 256, 0, stream>>>(w_qkv, w_gate, w_proj, PL);
  prep_tw<<<245, 256, 0, stream>>>(TW);
  // 1-2. X = rfft2(x, ortho): w-pass -> W0, h-pass (fwd,1/64) in place
  dftw_fwd<<<1024, 256, 0, stream>>>(x, W0f, TW + TWF_OFF);
  dfth<<<528, 256, 0, stream>>>(W0f, TW + TWH0_OFF);              // X planar in W0
  // 3. X -> token-major bf16x2 planes
  xpose_cplx<<<dim3(33, 8, 8), 256, 0, stream>>>(W0c, XP);
  // 4. attnf = conj(q)*k
  gemm_cplx_lds<0><<<2112, 256, 0, stream>>>(XP, PL + QKV_HI, PL + QKV_LO,
                                             PL + QKV_HI + 262144, PL + QKV_LO + 262144, W1c);
  // 5-6. attn = irfft2(attnf, ortho) -> d_out
  dfth<<<528, 256, 0, stream>>>(W1f, TW + TWH1_OFF);
  dftw_inv<<<1024, 256, 0, stream>>>(W1f, out, nullptr, TW + TWI_OFF);
  // 7. softmax over n per (b,c)
  softmax_n<<<BB * CC, 256, 0, stream>>>(out);
  // 8-9. A = rfft2(attn), backward norm (unscaled)
  dftw_fwd<<<1024, 256, 0, stream>>>(out, W1f, TW + TWF_OFF);
  dfth<<<528, 256, 0, stream>>>(W1f, TW + TWH2_OFF);              // A in W1
  // 10. v-GEMM fused with yf = conj(A)*v (in place on W1); XP dead after
  gemm_cplx_lds<1><<<2112, 256, 0, stream>>>(XP, PL + QKV_HI + 524288, PL + QKV_LO + 524288,
                                             nullptr, nullptr, W1c);
  // 11-12. y = irfft2(yf, ortho) -> W0f (planar real)
  dfth<<<528, 256, 0, stream>>>(W1f, TW + TWH1_OFF);
  dftw_inv<<<1024, 256, 0, stream>>>(W1f, W0f, nullptr, TW + TWI_OFF);
  // 13. gate: W0f *= silu(x @ w_gate^T + b_gate)   (GX <- xpose(x))
  xpose_real<<<dim3(64, 8, 8), 256, 0, stream>>>(x, GX);
  gemm_real_lds<0><<<4096, 256, 0, stream>>>(GX, PL + GATE_HI, PL + GATE_LO, b_gate, W0f);
  // 14-15. proj: out = (y.*t) @ w_proj^T + b_proj  (GX <- xpose(y.*t))
  xpose_real<<<dim3(64, 8, 8), 256, 0, stream>>>(W0f, GX);
  gemm_real_lds<1><<<4096, 256, 0, stream>>>(GX, PL + PROJ_HI, PL + PROJ_LO, b_proj, out);
}

// Round 7
// 988.702 us; speedup vs baseline: 1.4813x; 1.1507x over previous
//
#include <hip/hip_runtime.h>
#include <hip/hip_bf16.h>

// ---------------------------------------------------------------------------
// CirculantAttention on MI355X — round 7: m97-structure GEMMs (128-tiles,
// both operands async-LDS-staged, 2-barrier K-loop).
//
// r6 post-mortem: gemm_real_lds 192us, Mfma 10.7 / VALU 8.7 / Occ 74 —
// weight loads from global per-wave per-K-step (L2 latency, 2x duplicated)
// against only 12 MFMAs/K-step. r7: tiles 128x128 (real, v) / 128x64 (qk),
// BK=32, A AND W staged via global_load_lds (single buffer, 2 barriers,
// m97-proven). m runs over GLOBAL token index (16896 = 132*128 for complex;
// 32768 = 256*128 for real); b recovered in epilogue. d-fastest XCD swizzle.
// DFT / xpose / softmax / prep kernels unchanged from round 6.
// ws layout unchanged: 213,114,880 B.
// ---------------------------------------------------------------------------

#define BB 8
#define CC 512
#define HH 64
#define SS 4096   // HH*WW
#define WR 33     // WW/2+1
#define PP 2112   // HH*WR

#define TWOPI_64 0.09817477042468103f   // 2*pi/64

typedef float f32x4 __attribute__((ext_vector_type(4)));
typedef __bf16 bf16x8 __attribute__((ext_vector_type(8)));
typedef unsigned short ushort;
typedef ushort ushort8 __attribute__((ext_vector_type(8)));

// PL arena (ushort units)
#define QKV_HI 0
#define QKV_LO 786432
#define GATE_HI 1572864
#define GATE_LO 1835008
#define PROJ_HI 2097152
#define PROJ_LO 2359296

// TW arena (ushort units)
#define TWF_OFF 0
#define TWH0_OFF 12288
#define TWH1_OFF 47104
#define TWH2_OFF 81920
#define TWI_OFF 116736

#define SPX 8650752    // XP plane stride (ushort): 8*2112*512
#define SPG 16777216   // GX plane stride (ushort): 8*4096*512

__device__ __forceinline__ void split2(float x, ushort& h, ushort& l) {
  unsigned bx = __builtin_bit_cast(unsigned, x);
  h = (ushort)(bx >> 16);
  float hf = __builtin_bit_cast(float, bx & 0xffff0000u);
  float lf = x - hf;
  l = (ushort)(__builtin_bit_cast(unsigned, lf) >> 16);
}

__device__ __forceinline__ void gll16(const void* src, void* lds_dst) {
  __builtin_amdgcn_global_load_lds(
      (const __attribute__((address_space(1))) unsigned int*)src,
      (__attribute__((address_space(3))) unsigned int*)lds_dst, 16, 0, 0);
}

#define MFMA16(a, b, c) __builtin_amdgcn_mfma_f32_16x16x32_bf16(a, b, c, 0, 0, 0)

__device__ __forceinline__ void pack8(const float* f, bf16x8& hi, bf16x8& lo) {
  ushort8 hs, ls;
#pragma unroll
  for (int j = 0; j < 8; ++j) { ushort h, l; split2(f[j], h, l); hs[j] = h; ls[j] = l; }
  hi = __builtin_bit_cast(bf16x8, hs);
  lo = __builtin_bit_cast(bf16x8, ls);
}

// ===================== weight pre-split (once per launch) ==================
__global__ __launch_bounds__(256) void prep_w(
    const float* __restrict__ wqkv, const float* __restrict__ wg,
    const float* __restrict__ wp, ushort* __restrict__ planes) {
  int i = blockIdx.x * 256 + threadIdx.x;   // 0 .. 1,310,719
  float v; ushort *hp, *lp;
  if (i < 786432) {
    v = wqkv[i]; hp = planes + QKV_HI + i; lp = planes + QKV_LO + i;
  } else if (i < 1048576) {
    int j = i - 786432;
    v = wg[j]; hp = planes + GATE_HI + j; lp = planes + GATE_LO + j;
  } else {
    int j = i - 1048576;
    v = wp[j]; hp = planes + PROJ_HI + j; lp = planes + PROJ_LO + j;
  }
  ushort h, l; split2(v, h, l);
  *hp = h; *lp = l;
}

// ===================== twiddle pre-split (once per launch) =================
__global__ __launch_bounds__(256) void prep_tw(ushort* __restrict__ tw) {
  int i = blockIdx.x * 256 + threadIdx.x;
  if (i >= 62592) return;
  float val = 0.f; int base, plane, e;
  if (i < 5760) {                      // TWF [80][72]
    e = i; base = TWF_OFF; plane = 5760;
    int n = e / 72, k = e % 72;
    if (n < 66 && k < 64) {
      int kw = n >> 1;
      float s, c; sincosf(TWOPI_64 * (float)((k * kw) & 63), &s, &c);
      val = (n & 1) ? -s : c;
    }
  } else if (i < 57984) {              // TWH[v] [128][136]
    int j = i - 5760; int v = j / 17408; e = j % 17408;
    base = TWH0_OFF + v * 34816; plane = 17408;
    float sgn = (v == 1) ? 1.f : -1.f;
    float scale = (v == 0) ? (1.f / 64.f) : 1.f;
    int n = e / 136, k = e % 136;
    if (k < 128) {
      int kh = n >> 1, q = n & 1, h = k >> 1, p = k & 1;
      float s, c; sincosf(TWOPI_64 * (float)((h * kh) & 63), &s, &c);
      val = (p == q) ? c : ((q == 1) ? sgn * s : -sgn * s);
      val *= scale;
    }
  } else {                             // TWI [64][72]
    e = i - 57984; base = TWI_OFF; plane = 4608;
    int n = e / 72, k = e % 72;
    if (k < 64) {
      int kk = k >> 1, p = k & 1;
      float w = (kk == 0) ? 1.f : 2.f;
      float s, c; sincosf(TWOPI_64 * (float)((n * kk) & 63), &s, &c);
      val = (p ? -s : c) * w * (1.f / 64.f);
    }
  }
  ushort h, l; split2(val, h, l);
  tw[base + e] = h; tw[base + plane + e] = l;
}

// ===================== transpose+split: planar f32 -> token-major bf16 =====
__global__ __launch_bounds__(256) void xpose_cplx(
    const float2* __restrict__ in, ushort* __restrict__ xp) {
  __shared__ float2 tile[64][65];
  int b = blockIdx.z, p0 = blockIdx.x * 64, c0 = blockIdx.y * 64;
  int tid = threadIdx.x;
  int cr = tid >> 2, pq = (tid & 3) * 16;
  const float2* src = in + ((size_t)b * CC + c0 + cr) * PP + p0 + pq;
#pragma unroll
  for (int j = 0; j < 16; ++j) tile[cr][pq + j] = src[j];
  __syncthreads();
  int pr = tid >> 2, cq = (tid & 3) * 16;
  ushort8 rh[2], rl[2], ih[2], il[2];
#pragma unroll
  for (int g = 0; g < 2; ++g)
#pragma unroll
    for (int j = 0; j < 8; ++j) {
      float2 v = tile[cq + g * 8 + j][pr];
      ushort h, l;
      split2(v.x, h, l); rh[g][j] = h; rl[g][j] = l;
      split2(v.y, h, l); ih[g][j] = h; il[g][j] = l;
    }
  size_t ob = ((size_t)b * PP + p0 + pr) * CC + c0 + cq;
#pragma unroll
  for (int g = 0; g < 2; ++g) {
    *reinterpret_cast<ushort8*>(&xp[ob + g * 8]) = rh[g];
    *reinterpret_cast<ushort8*>(&xp[SPX + ob + g * 8]) = rl[g];
    *reinterpret_cast<ushort8*>(&xp[2 * SPX + ob + g * 8]) = ih[g];
    *reinterpret_cast<ushort8*>(&xp[3 * SPX + ob + g * 8]) = il[g];
  }
}

__global__ __launch_bounds__(256) void xpose_real(
    const float* __restrict__ in, ushort* __restrict__ gx) {
  __shared__ float tile[64][65];
  int b = blockIdx.z, s0 = blockIdx.x * 64, c0 = blockIdx.y * 64;
  int tid = threadIdx.x;
  int cr = tid >> 2, sq = (tid & 3) * 16;
  const float* src = in + ((size_t)b * CC + c0 + cr) * SS + s0 + sq;
#pragma unroll
  for (int j = 0; j < 16; ++j) tile[cr][sq + j] = src[j];
  __syncthreads();
  int sr = tid >> 2, cq = (tid & 3) * 16;
  ushort8 vh[2], vl[2];
#pragma unroll
  for (int g = 0; g < 2; ++g)
#pragma unroll
    for (int j = 0; j < 8; ++j) {
      ushort h, l; split2(tile[cq + g * 8 + j][sr], h, l);
      vh[g][j] = h; vl[g][j] = l;
    }
  size_t ob = ((size_t)b * SS + s0 + sr) * CC + c0 + cq;
#pragma unroll
  for (int g = 0; g < 2; ++g) {
    *reinterpret_cast<ushort8*>(&gx[ob + g * 8]) = vh[g];
    *reinterpret_cast<ushort8*>(&gx[SPG + ob + g * 8]) = vl[g];
  }
}

// ===================== complex GEMM: 128-token tile, A+W LDS-staged ========
// MODE 0: qk, d-tile 64, 4 W planes (w1h,w1l,w2h,w2l), out conj(q)*k
// MODE 1: v,  d-tile 128, 2 W planes, io = conj(A)*v in place
template <int MODE>
__global__ __launch_bounds__(256) void gemm_cplx_t(
    const ushort* __restrict__ xp,
    const ushort* __restrict__ w1_hi, const ushort* __restrict__ w1_lo,
    const ushort* __restrict__ w2_hi, const ushort* __restrict__ w2_lo,
    float2* __restrict__ io) {
  constexpr int DT = (MODE == 0) ? 2 : 4;       // d fragments per wave
  constexpr int WPL = (MODE == 0) ? 4 : 2;      // weight planes
  constexpr int WPS = (MODE == 0) ? 2048 : 4096; // plane stride (ushort)
  constexpr int NCOMBO = (MODE == 0) ? 4 : 2;
  __shared__ ushort sA[16384];                  // 4 planes x [128][32]  (32 KiB)
  __shared__ ushort sW[WPL * WPS];              // 16 KiB either mode

  int bid = blockIdx.x;
  int npx = (MODE == 0) ? 132 : 66;             // works per XCD chunk
  int work = (bid & 7) * npx + (bid >> 3);
  int mtile, d0;
  if (MODE == 0) { mtile = work >> 3; d0 = (work & 7) * 64; }
  else           { mtile = work >> 2; d0 = (work & 3) * 128; }
  int tok0 = mtile * 128;

  int tid = threadIdx.x;
  int lane = tid & 63, wid = tid >> 6;
  int fr = lane & 15, fq = lane >> 4;
  int wm = wid & 1, wd = wid >> 1;

  int srow = tid >> 2;
  int schunk = (tid & 3) ^ (srow & 3);
  int ldsw = (tid & 192) * 8;                   // wave-uniform seg base (ushort)
  const ushort* wp[4] = {w1_hi, w1_lo, w2_hi, w2_lo};

  f32x4 acc[4][DT][NCOMBO] = {};

  auto STAGE = [&](int k0) {
    size_t ga = (size_t)(tok0 + srow) * CC + k0 + schunk * 8;
#pragma unroll
    for (int p = 0; p < 4; ++p) {
      gll16(&xp[(size_t)p * SPX + ga], &sA[p * 4096 + ldsw]);
      gll16(&xp[(size_t)p * SPX + ga + (size_t)64 * CC], &sA[p * 4096 + 2048 + ldsw]);
    }
    size_t gw = (size_t)(d0 + srow) * CC + k0 + schunk * 8;
#pragma unroll
    for (int p = 0; p < WPL; ++p) {
      gll16(&wp[p][gw], &sW[p * WPS + ldsw]);
      if (MODE == 1)
        gll16(&wp[p][gw + (size_t)64 * CC], &sW[p * WPS + 2048 + ldsw]);
    }
  };

  STAGE(0);
  for (int t = 0; t < 16; ++t) {
    __syncthreads();   // stage of this K-slice complete (vmcnt drained)
    bf16x8 w1h[DT], w1l[DT], w2h[DT], w2l[DT];
#pragma unroll
    for (int dt = 0; dt < DT; ++dt) {
      int drow = wd * (DT * 16) + dt * 16 + fr;
      int off = drow * 32 + ((fq ^ (drow & 3)) * 8);
      w1h[dt] = *reinterpret_cast<const bf16x8*>(&sW[0 * WPS + off]);
      w1l[dt] = *reinterpret_cast<const bf16x8*>(&sW[1 * WPS + off]);
      if (MODE == 0) {
        w2h[dt] = *reinterpret_cast<const bf16x8*>(&sW[2 * WPS + off]);
        w2l[dt] = *reinterpret_cast<const bf16x8*>(&sW[3 * WPS + off]);
      }
    }
#pragma unroll
    for (int mt = 0; mt < 4; ++mt) {
      int mrow = wm * 64 + mt * 16 + fr;
      int offA = mrow * 32 + ((fq ^ (mrow & 3)) * 8);
      bf16x8 arh = *reinterpret_cast<const bf16x8*>(&sA[0 * 4096 + offA]);
      bf16x8 arl = *reinterpret_cast<const bf16x8*>(&sA[1 * 4096 + offA]);
      bf16x8 aih = *reinterpret_cast<const bf16x8*>(&sA[2 * 4096 + offA]);
      bf16x8 ail = *reinterpret_cast<const bf16x8*>(&sA[3 * 4096 + offA]);
#pragma unroll
      for (int dt = 0; dt < DT; ++dt) {
        acc[mt][dt][0] = MFMA16(arh, w1h[dt], acc[mt][dt][0]);
        acc[mt][dt][0] = MFMA16(arh, w1l[dt], acc[mt][dt][0]);
        acc[mt][dt][0] = MFMA16(arl, w1h[dt], acc[mt][dt][0]);
        acc[mt][dt][1] = MFMA16(aih, w1h[dt], acc[mt][dt][1]);
        acc[mt][dt][1] = MFMA16(aih, w1l[dt], acc[mt][dt][1]);
        acc[mt][dt][1] = MFMA16(ail, w1h[dt], acc[mt][dt][1]);
        if (MODE == 0) {
          acc[mt][dt][2] = MFMA16(arh, w2h[dt], acc[mt][dt][2]);
          acc[mt][dt][2] = MFMA16(arh, w2l[dt], acc[mt][dt][2]);
          acc[mt][dt][2] = MFMA16(arl, w2h[dt], acc[mt][dt][2]);
          acc[mt][dt][3] = MFMA16(aih, w2h[dt], acc[mt][dt][3]);
          acc[mt][dt][3] = MFMA16(aih, w2l[dt], acc[mt][dt][3]);
          acc[mt][dt][3] = MFMA16(ail, w2h[dt], acc[mt][dt][3]);
        }
      }
    }
    __syncthreads();   // all reads of this K-slice done
    if (t < 15) STAGE((t + 1) * 32);
  }

#pragma unroll
  for (int mt = 0; mt < 4; ++mt)
#pragma unroll
    for (int dt = 0; dt < DT; ++dt) {
      int d = d0 + wd * (DT * 16) + dt * 16 + fr;
#pragma unroll
      for (int r = 0; r < 4; ++r) {
        int tok = tok0 + wm * 64 + mt * 16 + fq * 4 + r;
        int b = tok / PP, p = tok - b * PP;
        size_t ob = ((size_t)b * CC + d) * PP + p;
        if (MODE == 0) {
          float qr = acc[mt][dt][0][r], qi = acc[mt][dt][1][r];
          float kr = acc[mt][dt][2][r], ki = acc[mt][dt][3][r];
          io[ob] = make_float2(qr * kr + qi * ki, qr * ki - qi * kr);
        } else {
          float vr = acc[mt][dt][0][r], vi = acc[mt][dt][1][r];
          float2 a = io[ob];
          io[ob] = make_float2(a.x * vr + a.y * vi, a.x * vi - a.y * vr);
        }
      }
    }
}

// ===================== real GEMM: 128x128 tile, A+W LDS-staged =============
// MODE 0: gate — io *= silu(z+bias)   MODE 1: proj — io = z + bias
template <int MODE>
__global__ __launch_bounds__(256) void gemm_real_t(
    const ushort* __restrict__ gx,
    const ushort* __restrict__ w_hi, const ushort* __restrict__ w_lo,
    const float* __restrict__ bias, float* __restrict__ io) {
  __shared__ ushort sA[8192];    // 2 planes x [128][32] (16 KiB)
  __shared__ ushort sW[8192];    // 2 planes x [128][32] (16 KiB)

  int bid = blockIdx.x;
  int work = (bid & 7) * 128 + (bid >> 3);   // 1024 blocks, d fastest
  int mtile = work >> 2, d0 = (work & 3) * 128;
  int tok0 = mtile * 128;

  int tid = threadIdx.x;
  int lane = tid & 63, wid = tid >> 6;
  int fr = lane & 15, fq = lane >> 4;
  int wm = wid & 1, wd = wid >> 1;

  int srow = tid >> 2;
  int schunk = (tid & 3) ^ (srow & 3);
  int ldsw = (tid & 192) * 8;

  f32x4 acc[4][4] = {};

  auto STAGE = [&](int k0) {
    size_t ga = (size_t)(tok0 + srow) * CC + k0 + schunk * 8;
    gll16(&gx[ga], &sA[ldsw]);
    gll16(&gx[SPG + ga], &sA[4096 + ldsw]);
    gll16(&gx[ga + (size_t)64 * CC], &sA[2048 + ldsw]);
    gll16(&gx[SPG + ga + (size_t)64 * CC], &sA[4096 + 2048 + ldsw]);
    size_t gw = (size_t)(d0 + srow) * CC + k0 + schunk * 8;
    gll16(&w_hi[gw], &sW[ldsw]);
    gll16(&w_lo[gw], &sW[4096 + ldsw]);
    gll16(&w_hi[gw + (size_t)64 * CC], &sW[2048 + ldsw]);
    gll16(&w_lo[gw + (size_t)64 * CC], &sW[4096 + 2048 + ldsw]);
  };

  STAGE(0);
  for (int t = 0; t < 16; ++t) {
    __syncthreads();
    bf16x8 wh[4], wl[4];
#pragma unroll
    for (int dt = 0; dt < 4; ++dt) {
      int drow = wd * 64 + dt * 16 + fr;
      int off = drow * 32 + ((fq ^ (drow & 3)) * 8);
      wh[dt] = *reinterpret_cast<const bf16x8*>(&sW[off]);
      wl[dt] = *reinterpret_cast<const bf16x8*>(&sW[4096 + off]);
    }
#pragma unroll
    for (int mt = 0; mt < 4; ++mt) {
      int mrow = wm * 64 + mt * 16 + fr;
      int offA = mrow * 32 + ((fq ^ (mrow & 3)) * 8);
      bf16x8 ah = *reinterpret_cast<const bf16x8*>(&sA[offA]);
      bf16x8 al = *reinterpret_cast<const bf16x8*>(&sA[4096 + offA]);
#pragma unroll
      for (int dt = 0; dt < 4; ++dt) {
        acc[mt][dt] = MFMA16(ah, wh[dt], acc[mt][dt]);
        acc[mt][dt] = MFMA16(ah, wl[dt], acc[mt][dt]);
        acc[mt][dt] = MFMA16(al, wh[dt], acc[mt][dt]);
      }
    }
    __syncthreads();
    if (t < 15) STAGE((t + 1) * 32);
  }

#pragma unroll
  for (int mt = 0; mt < 4; ++mt)
#pragma unroll
    for (int dt = 0; dt < 4; ++dt) {
      int d = d0 + wd * 64 + dt * 16 + fr;
      float bs = bias[d];
#pragma unroll
      for (int r = 0; r < 4; ++r) {
        int tok = tok0 + wm * 64 + mt * 16 + fq * 4 + r;
        int b = tok >> 12, s = tok & 4095;
        size_t ob = ((size_t)b * CC + d) * SS + s;
        float z = acc[mt][dt][r] + bs;
        if (MODE == 0) {
          float t2 = z / (1.f + __expf(-z));
          io[ob] *= t2;
        } else {
          io[ob] = z;
        }
      }
    }
}

// ===================== DFT-w forward: real rows -> interleaved complex =====
__global__ __launch_bounds__(256) void dftw_fwd(
    const float* __restrict__ in, float* __restrict__ outf,
    const ushort* __restrict__ tw) {
  __shared__ __align__(16) ushort B[12288];
  int tid = threadIdx.x;
  int lane = tid & 63, wid = tid >> 6;
  int fr = lane & 15, fq = lane >> 4;
#pragma unroll
  for (int i = 0; i < 6; ++i)
    gll16((const char*)tw + (i * 256 + tid) * 16,
          (char*)B + (i * 256 + (tid & 192)) * 16);
  __syncthreads();
  bf16x8 bh[5][2], bl[5][2];
#pragma unroll
  for (int nt = 0; nt < 5; ++nt)
#pragma unroll
    for (int ks = 0; ks < 2; ++ks) {
      int o = (nt * 16 + fr) * 72 + ks * 32 + fq * 8;
      bh[nt][ks] = *reinterpret_cast<const bf16x8*>(&B[o]);
      bl[nt][ks] = *reinterpret_cast<const bf16x8*>(&B[5760 + o]);
    }
  for (int chunk = blockIdx.x; chunk < 4096; chunk += gridDim.x) {
    int m0 = chunk * 64 + wid * 16;
    const float* rowp = in + (size_t)(m0 + fr) * 64;
    f32x4 acc[5] = {};
#pragma unroll
    for (int ks = 0; ks < 2; ++ks) {
      float4 v0 = *reinterpret_cast<const float4*>(rowp + ks * 32 + fq * 8);
      float4 v1 = *reinterpret_cast<const float4*>(rowp + ks * 32 + fq * 8 + 4);
      float f[8] = {v0.x, v0.y, v0.z, v0.w, v1.x, v1.y, v1.z, v1.w};
      bf16x8 ah, al; pack8(f, ah, al);
#pragma unroll
      for (int nt = 0; nt < 5; ++nt) {
        acc[nt] = MFMA16(ah, bh[nt][ks], acc[nt]);
        acc[nt] = MFMA16(ah, bl[nt][ks], acc[nt]);
        acc[nt] = MFMA16(al, bh[nt][ks], acc[nt]);
      }
    }
#pragma unroll
    for (int nt = 0; nt < 5; ++nt) {
      int n = nt * 16 + fr;
      if (n < 66) {
#pragma unroll
        for (int r = 0; r < 4; ++r) {
          int m = m0 + fq * 4 + r;
          outf[(size_t)m * 66 + n] = acc[nt][r];
        }
      }
    }
  }
}

// ===================== DFT-h: complex columns, IN-PLACE ====================
__global__ __launch_bounds__(256) void dfth(
    float* __restrict__ io, const ushort* __restrict__ tw) {
  __shared__ __align__(16) ushort B[34816];
  int tid = threadIdx.x;
  int lane = tid & 63, wid = tid >> 6;
  int fr = lane & 15, fq = lane >> 4;
#pragma unroll
  for (int i = 0; i < 17; ++i)
    gll16((const char*)tw + (i * 256 + tid) * 16,
          (char*)B + (i * 256 + (tid & 192)) * 16);
  __syncthreads();
  for (int chunk = blockIdx.x; chunk < 2112; chunk += gridDim.x) {
    int m0 = chunk * 64 + wid * 16;
    int rg = m0 + fr;
    int bc = rg / 33, kw = rg - bc * 33;
    const float* colp = io + ((size_t)bc * PP + kw) * 2;
    bf16x8 ah[4], al[4];
#pragma unroll
    for (int ks = 0; ks < 4; ++ks) {
      float f[8];
#pragma unroll
      for (int e = 0; e < 4; ++e) {
        float2 v = *reinterpret_cast<const float2*>(
            colp + (size_t)(ks * 16 + fq * 4 + e) * WR * 2);
        f[2 * e] = v.x; f[2 * e + 1] = v.y;
      }
      pack8(f, ah[ks], al[ks]);
    }
    f32x4 acc[8] = {};
#pragma unroll
    for (int ks = 0; ks < 4; ++ks)
#pragma unroll
      for (int nt = 0; nt < 8; ++nt) {
        int o = (nt * 16 + fr) * 136 + ks * 32 + fq * 8;
        bf16x8 wh = *reinterpret_cast<const bf16x8*>(&B[o]);
        bf16x8 wl = *reinterpret_cast<const bf16x8*>(&B[17408 + o]);
        acc[nt] = MFMA16(ah[ks], wh, acc[nt]);
        acc[nt] = MFMA16(ah[ks], wl, acc[nt]);
        acc[nt] = MFMA16(al[ks], wh, acc[nt]);
      }
#pragma unroll
    for (int r = 0; r < 4; ++r) {
      int m = m0 + fq * 4 + r;
      int bc2 = m / 33, kw2 = m - bc2 * 33;
      float* outp = io + ((size_t)bc2 * PP + kw2) * 2;
#pragma unroll
      for (int nt = 0; nt < 8; ++nt) {
        int n = nt * 16 + fr;
        int kh = n >> 1, q = n & 1;
        outp[(size_t)kh * WR * 2 + q] = acc[nt][r];
      }
    }
  }
}

// ===================== DFT-w inverse: interleaved complex -> real ==========
__global__ __launch_bounds__(256) void dftw_inv(
    const float* __restrict__ inf, float* __restrict__ out,
    const float* __restrict__ tmul, const ushort* __restrict__ tw) {
  __shared__ __align__(16) ushort B[10240];
  int tid = threadIdx.x;
  int lane = tid & 63, wid = tid >> 6;
  int fr = lane & 15, fq = lane >> 4;
#pragma unroll
  for (int i = 0; i < 5; ++i)
    gll16((const char*)tw + (i * 256 + tid) * 16,
          (char*)B + (i * 256 + (tid & 192)) * 16);
  __syncthreads();
  bf16x8 bh[4][2], bl[4][2];
#pragma unroll
  for (int nt = 0; nt < 4; ++nt)
#pragma unroll
    for (int ks = 0; ks < 2; ++ks) {
      int o = (nt * 16 + fr) * 72 + ks * 32 + fq * 8;
      bh[nt][ks] = *reinterpret_cast<const bf16x8*>(&B[o]);
      bl[nt][ks] = *reinterpret_cast<const bf16x8*>(&B[4608 + o]);
    }
  for (int chunk = blockIdx.x; chunk < 4096; chunk += gridDim.x) {
    int m0 = chunk * 64 + wid * 16;
    const float* rowp = inf + (size_t)(m0 + fr) * 66;
    f32x4 acc[4] = {};
#pragma unroll
    for (int ks = 0; ks < 2; ++ks) {
      float f[8];
#pragma unroll
      for (int e = 0; e < 4; ++e) {
        float2 v = *reinterpret_cast<const float2*>(rowp + ks * 32 + fq * 8 + 2 * e);
        f[2 * e] = v.x; f[2 * e + 1] = v.y;
      }
      bf16x8 ah, al; pack8(f, ah, al);
#pragma unroll
      for (int nt = 0; nt < 4; ++nt) {
        acc[nt] = MFMA16(ah, bh[nt][ks], acc[nt]);
        acc[nt] = MFMA16(ah, bl[nt][ks], acc[nt]);
        acc[nt] = MFMA16(al, bh[nt][ks], acc[nt]);
      }
    }
#pragma unroll
    for (int r = 0; r < 4; ++r) {
      int m = m0 + fq * 4 + r;
      float fr32 = inf[(size_t)m * 66 + 64] * (1.f / 64.f);
#pragma unroll
      for (int nt = 0; nt < 4; ++nt) {
        int x = nt * 16 + fr;
        float res = acc[nt][r] + ((x & 1) ? -fr32 : fr32);
        size_t o = (size_t)m * 64 + x;
        if (tmul) res *= tmul[o];
        out[o] = res;
      }
    }
  }
}

// ========================= softmax over n per (b,c) ========================
__global__ __launch_bounds__(256) void softmax_n(float* __restrict__ a) {
  __shared__ float red[16];
  int bc = blockIdx.x;
  float* p = a + (size_t)bc * SS;
  int t = threadIdx.x;
  float m = -1e30f;
  for (int i = t; i < SS; i += 256) m = fmaxf(m, p[i]);
#pragma unroll
  for (int off = 32; off > 0; off >>= 1) m = fmaxf(m, __shfl_down(m, off));
  if ((t & 63) == 0) red[t >> 6] = m;
  __syncthreads();
  if (t == 0) red[0] = fmaxf(fmaxf(red[0], red[1]), fmaxf(red[2], red[3]));
  __syncthreads();
  m = red[0];
  float s = 0.f;
  for (int i = t; i < SS; i += 256) s += __expf(p[i] - m);
#pragma unroll
  for (int off = 32; off > 0; off >>= 1) s += __shfl_down(s, off);
  if ((t & 63) == 0) red[8 + (t >> 6)] = s;
  __syncthreads();
  if (t == 0) red[4] = red[8] + red[9] + red[10] + red[11];
  __syncthreads();
  float inv = 1.f / red[4];
  for (int i = t; i < SS; i += 256) p[i] = __expf(p[i] - m) * inv;
}

// ===========================================================================
extern "C" void kernel_launch(void* const* d_in, const int* in_sizes, int n_in,
                              void* d_out, int out_size, void* d_ws, size_t ws_size,
                              hipStream_t stream) {
  const float* x      = (const float*)d_in[0];
  const float* w_qkv  = (const float*)d_in[1];
  const float* w_gate = (const float*)d_in[2];
  const float* b_gate = (const float*)d_in[3];
  const float* w_proj = (const float*)d_in[4];
  const float* b_proj = (const float*)d_in[5];
  float* out = (float*)d_out;

  char* ws = (char*)d_ws;
  float*  W0f = (float*)ws;                            // 69,206,016 B
  float2* W0c = (float2*)W0f;
  float*  W1f = (float*)(ws + 69206016);               // 69,206,016 B
  float2* W1c = (float2*)W1f;
  ushort* XP  = (ushort*)(ws + 138412032);             // 69,206,016 B (XP / GX share)
  ushort* GX  = XP;
  ushort* PL  = (ushort*)(ws + 207618048);             //  5,242,880 B
  ushort* TW  = (ushort*)(ws + 212860928);             //    253,952 B (end 213,114,880)

  // 0. pre-split weights + twiddles
  prep_w<<<5120, 256, 0, stream>>>(w_qkv, w_gate, w_proj, PL);
  prep_tw<<<245, 256, 0, stream>>>(TW);
  // 1-2. X = rfft2(x, ortho): w-pass -> W0, h-pass (fwd,1/64) in place
  dftw_fwd<<<1024, 256, 0, stream>>>(x, W0f, TW + TWF_OFF);
  dfth<<<528, 256, 0, stream>>>(W0f, TW + TWH0_OFF);              // X planar in W0
  // 3. X -> token-major bf16x2 planes
  xpose_cplx<<<dim3(33, 8, 8), 256, 0, stream>>>(W0c, XP);
  // 4. attnf = conj(q)*k
  gemm_cplx_t<0><<<1056, 256, 0, stream>>>(XP, PL + QKV_HI, PL + QKV_LO,
                                           PL + QKV_HI + 262144, PL + QKV_LO + 262144, W1c);
  // 5-6. attn = irfft2(attnf, ortho) -> d_out
  dfth<<<528, 256, 0, stream>>>(W1f, TW + TWH1_OFF);
  dftw_inv<<<1024, 256, 0, stream>>>(W1f, out, nullptr, TW + TWI_OFF);
  // 7. softmax over n per (b,c)
  softmax_n<<<BB * CC, 256, 0, stream>>>(out);
  // 8-9. A = rfft2(attn), backward norm (unscaled)
  dftw_fwd<<<1024, 256, 0, stream>>>(out, W1f, TW + TWF_OFF);
  dfth<<<528, 256, 0, stream>>>(W1f, TW + TWH2_OFF);              // A in W1
  // 10. v-GEMM fused with yf = conj(A)*v (in place on W1); XP dead after
  gemm_cplx_t<1><<<528, 256, 0, stream>>>(XP, PL + QKV_HI + 524288, PL + QKV_LO + 524288,
                                          nullptr, nullptr, W1c);
  // 11-12. y = irfft2(yf, ortho) -> W0f (planar real)
  dfth<<<528, 256, 0, stream>>>(W1f, TW + TWH1_OFF);
  dftw_inv<<<1024, 256, 0, stream>>>(W1f, W0f, nullptr, TW + TWI_OFF);
  // 13. gate: W0f *= silu(x @ w_gate^T + b_gate)   (GX <- xpose(x))
  xpose_real<<<dim3(64, 8, 8), 256, 0, stream>>>(x, GX);
  gemm_real_t<0><<<1024, 256, 0, stream>>>(GX, PL + GATE_HI, PL + GATE_LO, b_gate, W0f);
  // 14-15. proj: out = (y.*t) @ w_proj^T + b_proj  (GX <- xpose(y.*t))
  xpose_real<<<dim3(64, 8, 8), 256, 0, stream>>>(W0f, GX);
  gemm_real_t<1><<<1024, 256, 0, stream>>>(GX, PL + PROJ_HI, PL + PROJ_LO, b_proj, out);
}

// Round 8
// 891.850 us; speedup vs baseline: 1.6422x; 1.1086x over previous
//
#include <hip/hip_runtime.h>
#include <hip/hip_bf16.h>

// ---------------------------------------------------------------------------
// CirculantAttention on MI355X — round 8: complex GEMMs at 64x64 tiles for
// 4-blocks/CU residency.
//
// r7 post-mortem: gemm_cplx_t 192us @ VGPR=156 -> 8 waves/CU cap -> Occ 9.5%
// -> barrier drains fully exposed. r8: qk/v tiles 64x64 (grid 2112, 4 waves),
// acc 64/32 f32, __launch_bounds__(256,4) targeting VGPR<=128 + LDS 32/24KiB
// -> 4 blocks/CU; mt-outer loop keeps frag live-ranges small. Cross-block
// overlap hides the 2-barrier staging drain (m97 mechanism).
// Real GEMMs / DFTs / xposes / softmax / preps / ws identical to round 7.
// ---------------------------------------------------------------------------

#define BB 8
#define CC 512
#define HH 64
#define SS 4096   // HH*WW
#define WR 33     // WW/2+1
#define PP 2112   // HH*WR

#define TWOPI_64 0.09817477042468103f   // 2*pi/64

typedef float f32x4 __attribute__((ext_vector_type(4)));
typedef __bf16 bf16x8 __attribute__((ext_vector_type(8)));
typedef unsigned short ushort;
typedef ushort ushort8 __attribute__((ext_vector_type(8)));

// PL arena (ushort units)
#define QKV_HI 0
#define QKV_LO 786432
#define GATE_HI 1572864
#define GATE_LO 1835008
#define PROJ_HI 2097152
#define PROJ_LO 2359296

// TW arena (ushort units)
#define TWF_OFF 0
#define TWH0_OFF 12288
#define TWH1_OFF 47104
#define TWH2_OFF 81920
#define TWI_OFF 116736

#define SPX 8650752    // XP plane stride (ushort): 8*2112*512
#define SPG 16777216   // GX plane stride (ushort): 8*4096*512

__device__ __forceinline__ void split2(float x, ushort& h, ushort& l) {
  unsigned bx = __builtin_bit_cast(unsigned, x);
  h = (ushort)(bx >> 16);
  float hf = __builtin_bit_cast(float, bx & 0xffff0000u);
  float lf = x - hf;
  l = (ushort)(__builtin_bit_cast(unsigned, lf) >> 16);
}

__device__ __forceinline__ void gll16(const void* src, void* lds_dst) {
  __builtin_amdgcn_global_load_lds(
      (const __attribute__((address_space(1))) unsigned int*)src,
      (__attribute__((address_space(3))) unsigned int*)lds_dst, 16, 0, 0);
}

#define MFMA16(a, b, c) __builtin_amdgcn_mfma_f32_16x16x32_bf16(a, b, c, 0, 0, 0)

__device__ __forceinline__ void pack8(const float* f, bf16x8& hi, bf16x8& lo) {
  ushort8 hs, ls;
#pragma unroll
  for (int j = 0; j < 8; ++j) { ushort h, l; split2(f[j], h, l); hs[j] = h; ls[j] = l; }
  hi = __builtin_bit_cast(bf16x8, hs);
  lo = __builtin_bit_cast(bf16x8, ls);
}

// ===================== weight pre-split (once per launch) ==================
__global__ __launch_bounds__(256) void prep_w(
    const float* __restrict__ wqkv, const float* __restrict__ wg,
    const float* __restrict__ wp, ushort* __restrict__ planes) {
  int i = blockIdx.x * 256 + threadIdx.x;   // 0 .. 1,310,719
  float v; ushort *hp, *lp;
  if (i < 786432) {
    v = wqkv[i]; hp = planes + QKV_HI + i; lp = planes + QKV_LO + i;
  } else if (i < 1048576) {
    int j = i - 786432;
    v = wg[j]; hp = planes + GATE_HI + j; lp = planes + GATE_LO + j;
  } else {
    int j = i - 1048576;
    v = wp[j]; hp = planes + PROJ_HI + j; lp = planes + PROJ_LO + j;
  }
  ushort h, l; split2(v, h, l);
  *hp = h; *lp = l;
}

// ===================== twiddle pre-split (once per launch) =================
__global__ __launch_bounds__(256) void prep_tw(ushort* __restrict__ tw) {
  int i = blockIdx.x * 256 + threadIdx.x;
  if (i >= 62592) return;
  float val = 0.f; int base, plane, e;
  if (i < 5760) {                      // TWF [80][72]
    e = i; base = TWF_OFF; plane = 5760;
    int n = e / 72, k = e % 72;
    if (n < 66 && k < 64) {
      int kw = n >> 1;
      float s, c; sincosf(TWOPI_64 * (float)((k * kw) & 63), &s, &c);
      val = (n & 1) ? -s : c;
    }
  } else if (i < 57984) {              // TWH[v] [128][136]
    int j = i - 5760; int v = j / 17408; e = j % 17408;
    base = TWH0_OFF + v * 34816; plane = 17408;
    float sgn = (v == 1) ? 1.f : -1.f;
    float scale = (v == 0) ? (1.f / 64.f) : 1.f;
    int n = e / 136, k = e % 136;
    if (k < 128) {
      int kh = n >> 1, q = n & 1, h = k >> 1, p = k & 1;
      float s, c; sincosf(TWOPI_64 * (float)((h * kh) & 63), &s, &c);
      val = (p == q) ? c : ((q == 1) ? sgn * s : -sgn * s);
      val *= scale;
    }
  } else {                             // TWI [64][72]
    e = i - 57984; base = TWI_OFF; plane = 4608;
    int n = e / 72, k = e % 72;
    if (k < 64) {
      int kk = k >> 1, p = k & 1;
      float w = (kk == 0) ? 1.f : 2.f;
      float s, c; sincosf(TWOPI_64 * (float)((n * kk) & 63), &s, &c);
      val = (p ? -s : c) * w * (1.f / 64.f);
    }
  }
  ushort h, l; split2(val, h, l);
  tw[base + e] = h; tw[base + plane + e] = l;
}

// ===================== transpose+split: planar f32 -> token-major bf16 =====
__global__ __launch_bounds__(256) void xpose_cplx(
    const float2* __restrict__ in, ushort* __restrict__ xp) {
  __shared__ float2 tile[64][65];
  int b = blockIdx.z, p0 = blockIdx.x * 64, c0 = blockIdx.y * 64;
  int tid = threadIdx.x;
  int cr = tid >> 2, pq = (tid & 3) * 16;
  const float2* src = in + ((size_t)b * CC + c0 + cr) * PP + p0 + pq;
#pragma unroll
  for (int j = 0; j < 16; ++j) tile[cr][pq + j] = src[j];
  __syncthreads();
  int pr = tid >> 2, cq = (tid & 3) * 16;
  ushort8 rh[2], rl[2], ih[2], il[2];
#pragma unroll
  for (int g = 0; g < 2; ++g)
#pragma unroll
    for (int j = 0; j < 8; ++j) {
      float2 v = tile[cq + g * 8 + j][pr];
      ushort h, l;
      split2(v.x, h, l); rh[g][j] = h; rl[g][j] = l;
      split2(v.y, h, l); ih[g][j] = h; il[g][j] = l;
    }
  size_t ob = ((size_t)b * PP + p0 + pr) * CC + c0 + cq;
#pragma unroll
  for (int g = 0; g < 2; ++g) {
    *reinterpret_cast<ushort8*>(&xp[ob + g * 8]) = rh[g];
    *reinterpret_cast<ushort8*>(&xp[SPX + ob + g * 8]) = rl[g];
    *reinterpret_cast<ushort8*>(&xp[2 * SPX + ob + g * 8]) = ih[g];
    *reinterpret_cast<ushort8*>(&xp[3 * SPX + ob + g * 8]) = il[g];
  }
}

__global__ __launch_bounds__(256) void xpose_real(
    const float* __restrict__ in, ushort* __restrict__ gx) {
  __shared__ float tile[64][65];
  int b = blockIdx.z, s0 = blockIdx.x * 64, c0 = blockIdx.y * 64;
  int tid = threadIdx.x;
  int cr = tid >> 2, sq = (tid & 3) * 16;
  const float* src = in + ((size_t)b * CC + c0 + cr) * SS + s0 + sq;
#pragma unroll
  for (int j = 0; j < 16; ++j) tile[cr][sq + j] = src[j];
  __syncthreads();
  int sr = tid >> 2, cq = (tid & 3) * 16;
  ushort8 vh[2], vl[2];
#pragma unroll
  for (int g = 0; g < 2; ++g)
#pragma unroll
    for (int j = 0; j < 8; ++j) {
      ushort h, l; split2(tile[cq + g * 8 + j][sr], h, l);
      vh[g][j] = h; vl[g][j] = l;
    }
  size_t ob = ((size_t)b * SS + s0 + sr) * CC + c0 + cq;
#pragma unroll
  for (int g = 0; g < 2; ++g) {
    *reinterpret_cast<ushort8*>(&gx[ob + g * 8]) = vh[g];
    *reinterpret_cast<ushort8*>(&gx[SPG + ob + g * 8]) = vl[g];
  }
}

// ===================== complex GEMM: 64x64 tile, A+W LDS-staged ============
// MODE 0: qk (out attnf = conj(q)*k)  MODE 1: v (io = conj(A)*v in place)
// 4 waves = wm(2) x wd(2); per wave 32m x 32d; acc[2][2][NC] = 64/32 VGPR.
template <int MODE>
__global__ __launch_bounds__(256, 4) void gemm_cplx_s(
    const ushort* __restrict__ xp,
    const ushort* __restrict__ w1_hi, const ushort* __restrict__ w1_lo,
    const ushort* __restrict__ w2_hi, const ushort* __restrict__ w2_lo,
    float2* __restrict__ io) {
  constexpr int WPL = (MODE == 0) ? 4 : 2;
  constexpr int NC = (MODE == 0) ? 4 : 2;
  __shared__ ushort sA[4 * 2048];          // 16 KiB: 4 planes x [64][32]
  __shared__ ushort sW[WPL * 2048];        // 16 / 8 KiB

  int bid = blockIdx.x;
  // 2112 blocks = 8 XCD chunks x 264 works, d-tile fastest within chunk
  int work = (bid & 7) * 264 + (bid >> 3);
  int mtile = work >> 3, d0 = (work & 7) * 64;
  int tok0 = mtile * 64;

  int tid = threadIdx.x;
  int lane = tid & 63, wid = tid >> 6;
  int fr = lane & 15, fq = lane >> 4;
  int wm = wid & 1, wd = wid >> 1;

  int srow = tid >> 2;
  int schunk = (tid & 3) ^ (srow & 3);
  int ldsw = (tid & 192) * 8;              // wave-uniform 1 KiB segment base
  const ushort* wp0 = w1_hi; const ushort* wp1 = w1_lo;
  const ushort* wp2 = w2_hi; const ushort* wp3 = w2_lo;

  f32x4 acc[2][2][NC] = {};

  auto STAGE = [&](int k0) {
    size_t ga = (size_t)(tok0 + srow) * CC + k0 + schunk * 8;
#pragma unroll
    for (int p = 0; p < 4; ++p)
      gll16(&xp[(size_t)p * SPX + ga], &sA[p * 2048 + ldsw]);
    size_t gw = (size_t)(d0 + srow) * CC + k0 + schunk * 8;
    gll16(&wp0[gw], &sW[0 * 2048 + ldsw]);
    gll16(&wp1[gw], &sW[1 * 2048 + ldsw]);
    if (MODE == 0) {
      gll16(&wp2[gw], &sW[2 * 2048 + ldsw]);
      gll16(&wp3[gw], &sW[3 * 2048 + ldsw]);
    }
  };

  STAGE(0);
  for (int t = 0; t < 16; ++t) {
    __syncthreads();   // staging of this K-slice complete
#pragma unroll
    for (int mt = 0; mt < 2; ++mt) {
      int mrow = wm * 32 + mt * 16 + fr;
      int offA = mrow * 32 + ((fq ^ (mrow & 3)) * 8);
      bf16x8 arh = *reinterpret_cast<const bf16x8*>(&sA[0 * 2048 + offA]);
      bf16x8 arl = *reinterpret_cast<const bf16x8*>(&sA[1 * 2048 + offA]);
      bf16x8 aih = *reinterpret_cast<const bf16x8*>(&sA[2 * 2048 + offA]);
      bf16x8 ail = *reinterpret_cast<const bf16x8*>(&sA[3 * 2048 + offA]);
#pragma unroll
      for (int dt = 0; dt < 2; ++dt) {
        int drow = wd * 32 + dt * 16 + fr;
        int offW = drow * 32 + ((fq ^ (drow & 3)) * 8);
        bf16x8 w1h = *reinterpret_cast<const bf16x8*>(&sW[0 * 2048 + offW]);
        bf16x8 w1l = *reinterpret_cast<const bf16x8*>(&sW[1 * 2048 + offW]);
        acc[mt][dt][0] = MFMA16(arh, w1h, acc[mt][dt][0]);
        acc[mt][dt][0] = MFMA16(arh, w1l, acc[mt][dt][0]);
        acc[mt][dt][0] = MFMA16(arl, w1h, acc[mt][dt][0]);
        acc[mt][dt][1] = MFMA16(aih, w1h, acc[mt][dt][1]);
        acc[mt][dt][1] = MFMA16(aih, w1l, acc[mt][dt][1]);
        acc[mt][dt][1] = MFMA16(ail, w1h, acc[mt][dt][1]);
        if (MODE == 0) {
          bf16x8 w2h = *reinterpret_cast<const bf16x8*>(&sW[2 * 2048 + offW]);
          bf16x8 w2l = *reinterpret_cast<const bf16x8*>(&sW[3 * 2048 + offW]);
          acc[mt][dt][2] = MFMA16(arh, w2h, acc[mt][dt][2]);
          acc[mt][dt][2] = MFMA16(arh, w2l, acc[mt][dt][2]);
          acc[mt][dt][2] = MFMA16(arl, w2h, acc[mt][dt][2]);
          acc[mt][dt][3] = MFMA16(aih, w2h, acc[mt][dt][3]);
          acc[mt][dt][3] = MFMA16(aih, w2l, acc[mt][dt][3]);
          acc[mt][dt][3] = MFMA16(ail, w2h, acc[mt][dt][3]);
        }
      }
    }
    __syncthreads();   // reads done; safe to overwrite
    if (t < 15) STAGE((t + 1) * 32);
  }

#pragma unroll
  for (int mt = 0; mt < 2; ++mt)
#pragma unroll
    for (int dt = 0; dt < 2; ++dt) {
      int d = d0 + wd * 32 + dt * 16 + fr;
#pragma unroll
      for (int r = 0; r < 4; ++r) {
        int tok = tok0 + wm * 32 + mt * 16 + fq * 4 + r;
        int b = tok / PP, p = tok - b * PP;
        size_t ob = ((size_t)b * CC + d) * PP + p;
        if (MODE == 0) {
          float qr = acc[mt][dt][0][r], qi = acc[mt][dt][1][r];
          float kr = acc[mt][dt][2][r], ki = acc[mt][dt][3][r];
          io[ob] = make_float2(qr * kr + qi * ki, qr * ki - qi * kr);
        } else {
          float vr = acc[mt][dt][0][r], vi = acc[mt][dt][1][r];
          float2 a = io[ob];
          io[ob] = make_float2(a.x * vr + a.y * vi, a.x * vi - a.y * vr);
        }
      }
    }
}

// ===================== real GEMM: 128x128 tile, A+W LDS-staged =============
// MODE 0: gate — io *= silu(z+bias)   MODE 1: proj — io = z + bias
template <int MODE>
__global__ __launch_bounds__(256) void gemm_real_t(
    const ushort* __restrict__ gx,
    const ushort* __restrict__ w_hi, const ushort* __restrict__ w_lo,
    const float* __restrict__ bias, float* __restrict__ io) {
  __shared__ ushort sA[8192];    // 2 planes x [128][32] (16 KiB)
  __shared__ ushort sW[8192];    // 2 planes x [128][32] (16 KiB)

  int bid = blockIdx.x;
  int work = (bid & 7) * 128 + (bid >> 3);   // 1024 blocks, d fastest
  int mtile = work >> 2, d0 = (work & 3) * 128;
  int tok0 = mtile * 128;

  int tid = threadIdx.x;
  int lane = tid & 63, wid = tid >> 6;
  int fr = lane & 15, fq = lane >> 4;
  int wm = wid & 1, wd = wid >> 1;

  int srow = tid >> 2;
  int schunk = (tid & 3) ^ (srow & 3);
  int ldsw = (tid & 192) * 8;

  f32x4 acc[4][4] = {};

  auto STAGE = [&](int k0) {
    size_t ga = (size_t)(tok0 + srow) * CC + k0 + schunk * 8;
    gll16(&gx[ga], &sA[ldsw]);
    gll16(&gx[SPG + ga], &sA[4096 + ldsw]);
    gll16(&gx[ga + (size_t)64 * CC], &sA[2048 + ldsw]);
    gll16(&gx[SPG + ga + (size_t)64 * CC], &sA[4096 + 2048 + ldsw]);
    size_t gw = (size_t)(d0 + srow) * CC + k0 + schunk * 8;
    gll16(&w_hi[gw], &sW[ldsw]);
    gll16(&w_lo[gw], &sW[4096 + ldsw]);
    gll16(&w_hi[gw + (size_t)64 * CC], &sW[2048 + ldsw]);
    gll16(&w_lo[gw + (size_t)64 * CC], &sW[4096 + 2048 + ldsw]);
  };

  STAGE(0);
  for (int t = 0; t < 16; ++t) {
    __syncthreads();
    bf16x8 wh[4], wl[4];
#pragma unroll
    for (int dt = 0; dt < 4; ++dt) {
      int drow = wd * 64 + dt * 16 + fr;
      int off = drow * 32 + ((fq ^ (drow & 3)) * 8);
      wh[dt] = *reinterpret_cast<const bf16x8*>(&sW[off]);
      wl[dt] = *reinterpret_cast<const bf16x8*>(&sW[4096 + off]);
    }
#pragma unroll
    for (int mt = 0; mt < 4; ++mt) {
      int mrow = wm * 64 + mt * 16 + fr;
      int offA = mrow * 32 + ((fq ^ (mrow & 3)) * 8);
      bf16x8 ah = *reinterpret_cast<const bf16x8*>(&sA[offA]);
      bf16x8 al = *reinterpret_cast<const bf16x8*>(&sA[4096 + offA]);
#pragma unroll
      for (int dt = 0; dt < 4; ++dt) {
        acc[mt][dt] = MFMA16(ah, wh[dt], acc[mt][dt]);
        acc[mt][dt] = MFMA16(ah, wl[dt], acc[mt][dt]);
        acc[mt][dt] = MFMA16(al, wh[dt], acc[mt][dt]);
      }
    }
    __syncthreads();
    if (t < 15) STAGE((t + 1) * 32);
  }

#pragma unroll
  for (int mt = 0; mt < 4; ++mt)
#pragma unroll
    for (int dt = 0; dt < 4; ++dt) {
      int d = d0 + wd * 64 + dt * 16 + fr;
      float bs = bias[d];
#pragma unroll
      for (int r = 0; r < 4; ++r) {
        int tok = tok0 + wm * 64 + mt * 16 + fq * 4 + r;
        int b = tok >> 12, s = tok & 4095;
        size_t ob = ((size_t)b * CC + d) * SS + s;
        float z = acc[mt][dt][r] + bs;
        if (MODE == 0) {
          float t2 = z / (1.f + __expf(-z));
          io[ob] *= t2;
        } else {
          io[ob] = z;
        }
      }
    }
}

// ===================== DFT-w forward: real rows -> interleaved complex =====
__global__ __launch_bounds__(256) void dftw_fwd(
    const float* __restrict__ in, float* __restrict__ outf,
    const ushort* __restrict__ tw) {
  __shared__ __align__(16) ushort B[12288];
  int tid = threadIdx.x;
  int lane = tid & 63, wid = tid >> 6;
  int fr = lane & 15, fq = lane >> 4;
#pragma unroll
  for (int i = 0; i < 6; ++i)
    gll16((const char*)tw + (i * 256 + tid) * 16,
          (char*)B + (i * 256 + (tid & 192)) * 16);
  __syncthreads();
  bf16x8 bh[5][2], bl[5][2];
#pragma unroll
  for (int nt = 0; nt < 5; ++nt)
#pragma unroll
    for (int ks = 0; ks < 2; ++ks) {
      int o = (nt * 16 + fr) * 72 + ks * 32 + fq * 8;
      bh[nt][ks] = *reinterpret_cast<const bf16x8*>(&B[o]);
      bl[nt][ks] = *reinterpret_cast<const bf16x8*>(&B[5760 + o]);
    }
  for (int chunk = blockIdx.x; chunk < 4096; chunk += gridDim.x) {
    int m0 = chunk * 64 + wid * 16;
    const float* rowp = in + (size_t)(m0 + fr) * 64;
    f32x4 acc[5] = {};
#pragma unroll
    for (int ks = 0; ks < 2; ++ks) {
      float4 v0 = *reinterpret_cast<const float4*>(rowp + ks * 32 + fq * 8);
      float4 v1 = *reinterpret_cast<const float4*>(rowp + ks * 32 + fq * 8 + 4);
      float f[8] = {v0.x, v0.y, v0.z, v0.w, v1.x, v1.y, v1.z, v1.w};
      bf16x8 ah, al; pack8(f, ah, al);
#pragma unroll
      for (int nt = 0; nt < 5; ++nt) {
        acc[nt] = MFMA16(ah, bh[nt][ks], acc[nt]);
        acc[nt] = MFMA16(ah, bl[nt][ks], acc[nt]);
        acc[nt] = MFMA16(al, bh[nt][ks], acc[nt]);
      }
    }
#pragma unroll
    for (int nt = 0; nt < 5; ++nt) {
      int n = nt * 16 + fr;
      if (n < 66) {
#pragma unroll
        for (int r = 0; r < 4; ++r) {
          int m = m0 + fq * 4 + r;
          outf[(size_t)m * 66 + n] = acc[nt][r];
        }
      }
    }
  }
}

// ===================== DFT-h: complex columns, IN-PLACE ====================
__global__ __launch_bounds__(256) void dfth(
    float* __restrict__ io, const ushort* __restrict__ tw) {
  __shared__ __align__(16) ushort B[34816];
  int tid = threadIdx.x;
  int lane = tid & 63, wid = tid >> 6;
  int fr = lane & 15, fq = lane >> 4;
#pragma unroll
  for (int i = 0; i < 17; ++i)
    gll16((const char*)tw + (i * 256 + tid) * 16,
          (char*)B + (i * 256 + (tid & 192)) * 16);
  __syncthreads();
  for (int chunk = blockIdx.x; chunk < 2112; chunk += gridDim.x) {
    int m0 = chunk * 64 + wid * 16;
    int rg = m0 + fr;
    int bc = rg / 33, kw = rg - bc * 33;
    const float* colp = io + ((size_t)bc * PP + kw) * 2;
    bf16x8 ah[4], al[4];
#pragma unroll
    for (int ks = 0; ks < 4; ++ks) {
      float f[8];
#pragma unroll
      for (int e = 0; e < 4; ++e) {
        float2 v = *reinterpret_cast<const float2*>(
            colp + (size_t)(ks * 16 + fq * 4 + e) * WR * 2);
        f[2 * e] = v.x; f[2 * e + 1] = v.y;
      }
      pack8(f, ah[ks], al[ks]);
    }
    f32x4 acc[8] = {};
#pragma unroll
    for (int ks = 0; ks < 4; ++ks)
#pragma unroll
      for (int nt = 0; nt < 8; ++nt) {
        int o = (nt * 16 + fr) * 136 + ks * 32 + fq * 8;
        bf16x8 wh = *reinterpret_cast<const bf16x8*>(&B[o]);
        bf16x8 wl = *reinterpret_cast<const bf16x8*>(&B[17408 + o]);
        acc[nt] = MFMA16(ah[ks], wh, acc[nt]);
        acc[nt] = MFMA16(ah[ks], wl, acc[nt]);
        acc[nt] = MFMA16(al[ks], wh, acc[nt]);
      }
#pragma unroll
    for (int r = 0; r < 4; ++r) {
      int m = m0 + fq * 4 + r;
      int bc2 = m / 33, kw2 = m - bc2 * 33;
      float* outp = io + ((size_t)bc2 * PP + kw2) * 2;
#pragma unroll
      for (int nt = 0; nt < 8; ++nt) {
        int n = nt * 16 + fr;
        int kh = n >> 1, q = n & 1;
        outp[(size_t)kh * WR * 2 + q] = acc[nt][r];
      }
    }
  }
}

// ===================== DFT-w inverse: interleaved complex -> real ==========
__global__ __launch_bounds__(256) void dftw_inv(
    const float* __restrict__ inf, float* __restrict__ out,
    const float* __restrict__ tmul, const ushort* __restrict__ tw) {
  __shared__ __align__(16) ushort B[10240];
  int tid = threadIdx.x;
  int lane = tid & 63, wid = tid >> 6;
  int fr = lane & 15, fq = lane >> 4;
#pragma unroll
  for (int i = 0; i < 5; ++i)
    gll16((const char*)tw + (i * 256 + tid) * 16,
          (char*)B + (i * 256 + (tid & 192)) * 16);
  __syncthreads();
  bf16x8 bh[4][2], bl[4][2];
#pragma unroll
  for (int nt = 0; nt < 4; ++nt)
#pragma unroll
    for (int ks = 0; ks < 2; ++ks) {
      int o = (nt * 16 + fr) * 72 + ks * 32 + fq * 8;
      bh[nt][ks] = *reinterpret_cast<const bf16x8*>(&B[o]);
      bl[nt][ks] = *reinterpret_cast<const bf16x8*>(&B[4608 + o]);
    }
  for (int chunk = blockIdx.x; chunk < 4096; chunk += gridDim.x) {
    int m0 = chunk * 64 + wid * 16;
    const float* rowp = inf + (size_t)(m0 + fr) * 66;
    f32x4 acc[4] = {};
#pragma unroll
    for (int ks = 0; ks < 2; ++ks) {
      float f[8];
#pragma unroll
      for (int e = 0; e < 4; ++e) {
        float2 v = *reinterpret_cast<const float2*>(rowp + ks * 32 + fq * 8 + 2 * e);
        f[2 * e] = v.x; f[2 * e + 1] = v.y;
      }
      bf16x8 ah, al; pack8(f, ah, al);
#pragma unroll
      for (int nt = 0; nt < 4; ++nt) {
        acc[nt] = MFMA16(ah, bh[nt][ks], acc[nt]);
        acc[nt] = MFMA16(ah, bl[nt][ks], acc[nt]);
        acc[nt] = MFMA16(al, bh[nt][ks], acc[nt]);
      }
    }
#pragma unroll
    for (int r = 0; r < 4; ++r) {
      int m = m0 + fq * 4 + r;
      float fr32 = inf[(size_t)m * 66 + 64] * (1.f / 64.f);
#pragma unroll
      for (int nt = 0; nt < 4; ++nt) {
        int x = nt * 16 + fr;
        float res = acc[nt][r] + ((x & 1) ? -fr32 : fr32);
        size_t o = (size_t)m * 64 + x;
        if (tmul) res *= tmul[o];
        out[o] = res;
      }
    }
  }
}

// ========================= softmax over n per (b,c) ========================
__global__ __launch_bounds__(256) void softmax_n(float* __restrict__ a) {
  __shared__ float red[16];
  int bc = blockIdx.x;
  float* p = a + (size_t)bc * SS;
  int t = threadIdx.x;
  float m = -1e30f;
  for (int i = t; i < SS; i += 256) m = fmaxf(m, p[i]);
#pragma unroll
  for (int off = 32; off > 0; off >>= 1) m = fmaxf(m, __shfl_down(m, off));
  if ((t & 63) == 0) red[t >> 6] = m;
  __syncthreads();
  if (t == 0) red[0] = fmaxf(fmaxf(red[0], red[1]), fmaxf(red[2], red[3]));
  __syncthreads();
  m = red[0];
  float s = 0.f;
  for (int i = t; i < SS; i += 256) s += __expf(p[i] - m);
#pragma unroll
  for (int off = 32; off > 0; off >>= 1) s += __shfl_down(s, off);
  if ((t & 63) == 0) red[8 + (t >> 6)] = s;
  __syncthreads();
  if (t == 0) red[4] = red[8] + red[9] + red[10] + red[11];
  __syncthreads();
  float inv = 1.f / red[4];
  for (int i = t; i < SS; i += 256) p[i] = __expf(p[i] - m) * inv;
}

// ===========================================================================
extern "C" void kernel_launch(void* const* d_in, const int* in_sizes, int n_in,
                              void* d_out, int out_size, void* d_ws, size_t ws_size,
                              hipStream_t stream) {
  const float* x      = (const float*)d_in[0];
  const float* w_qkv  = (const float*)d_in[1];
  const float* w_gate = (const float*)d_in[2];
  const float* b_gate = (const float*)d_in[3];
  const float* w_proj = (const float*)d_in[4];
  const float* b_proj = (const float*)d_in[5];
  float* out = (float*)d_out;

  char* ws = (char*)d_ws;
  float*  W0f = (float*)ws;                            // 69,206,016 B
  float2* W0c = (float2*)W0f;
  float*  W1f = (float*)(ws + 69206016);               // 69,206,016 B
  float2* W1c = (float2*)W1f;
  ushort* XP  = (ushort*)(ws + 138412032);             // 69,206,016 B (XP / GX share)
  ushort* GX  = XP;
  ushort* PL  = (ushort*)(ws + 207618048);             //  5,242,880 B
  ushort* TW  = (ushort*)(ws + 212860928);             //    253,952 B (end 213,114,880)

  // 0. pre-split weights + twiddles
  prep_w<<<5120, 256, 0, stream>>>(w_qkv, w_gate, w_proj, PL);
  prep_tw<<<245, 256, 0, stream>>>(TW);
  // 1-2. X = rfft2(x, ortho): w-pass -> W0, h-pass (fwd,1/64) in place
  dftw_fwd<<<1024, 256, 0, stream>>>(x, W0f, TW + TWF_OFF);
  dfth<<<528, 256, 0, stream>>>(W0f, TW + TWH0_OFF);              // X planar in W0
  // 3. X -> token-major bf16x2 planes
  xpose_cplx<<<dim3(33, 8, 8), 256, 0, stream>>>(W0c, XP);
  // 4. attnf = conj(q)*k
  gemm_cplx_s<0><<<2112, 256, 0, stream>>>(XP, PL + QKV_HI, PL + QKV_LO,
                                           PL + QKV_HI + 262144, PL + QKV_LO + 262144, W1c);
  // 5-6. attn = irfft2(attnf, ortho) -> d_out
  dfth<<<528, 256, 0, stream>>>(W1f, TW + TWH1_OFF);
  dftw_inv<<<1024, 256, 0, stream>>>(W1f, out, nullptr, TW + TWI_OFF);
  // 7. softmax over n per (b,c)
  softmax_n<<<BB * CC, 256, 0, stream>>>(out);
  // 8-9. A = rfft2(attn), backward norm (unscaled)
  dftw_fwd<<<1024, 256, 0, stream>>>(out, W1f, TW + TWF_OFF);
  dfth<<<528, 256, 0, stream>>>(W1f, TW + TWH2_OFF);              // A in W1
  // 10. v-GEMM fused with yf = conj(A)*v (in place on W1); XP dead after
  gemm_cplx_s<1><<<2112, 256, 0, stream>>>(XP, PL + QKV_HI + 524288, PL + QKV_LO + 524288,
                                           nullptr, nullptr, W1c);
  // 11-12. y = irfft2(yf, ortho) -> W0f (planar real)
  dfth<<<528, 256, 0, stream>>>(W1f, TW + TWH1_OFF);
  dftw_inv<<<1024, 256, 0, stream>>>(W1f, W0f, nullptr, TW + TWI_OFF);
  // 13. gate: W0f *= silu(x @ w_gate^T + b_gate)   (GX <- xpose(x))
  xpose_real<<<dim3(64, 8, 8), 256, 0, stream>>>(x, GX);
  gemm_real_t<0><<<1024, 256, 0, stream>>>(GX, PL + GATE_HI, PL + GATE_LO, b_gate, W0f);
  // 14-15. proj: out = (y.*t) @ w_proj^T + b_proj  (GX <- xpose(y.*t))
  xpose_real<<<dim3(64, 8, 8), 256, 0, stream>>>(W0f, GX);
  gemm_real_t<1><<<1024, 256, 0, stream>>>(GX, PL + PROJ_HI, PL + PROJ_LO, b_proj, out);
}